// Round 15
// baseline (111.823 us; speedup 1.0000x reference)
//
#include <hip/hip_runtime.h>
#include <stdint.h>

#define B_ 2
#define S_ 2048
#define E_ 1024
#define H_ 16
#define HD_ 64
#define N_ (B_*S_)
#define BH_ (B_*H_)
#define GAMMA 0.01f

typedef __attribute__((ext_vector_type(8))) short bf16x8;
typedef __attribute__((ext_vector_type(4))) float f32x4;
typedef __attribute__((ext_vector_type(2))) float f32x2;
typedef __attribute__((ext_vector_type(16))) float f32x16;
typedef unsigned short u16;
typedef unsigned int u32;

// byte-level XOR swizzle within a 128B row
#define SWZ(row, kb) ((kb) ^ (((row)&7)<<4))

__device__ __forceinline__ u16 f2bf(float f){
  union { float f; u32 u; } v; v.f = f;
  return (u16)((v.u + 0x7FFFu + ((v.u>>16)&1u)) >> 16);
}

__device__ __forceinline__ float bf2f(u16 u){
  union { u32 u; float f; } v; v.u = ((u32)u)<<16; return v.f;
}

__device__ __forceinline__ u32 cvt_pk_bf16(float lo, float hi){
  u32 r; asm("v_cvt_pk_bf16_f32 %0, %1, %2" : "=v"(r) : "v"(lo), "v"(hi)); return r;
}

__device__ __forceinline__ uint4 pack8(float4 a, float4 b){
  uint4 r;
  r.x = cvt_pk_bf16(a.x, a.y);
  r.y = cvt_pk_bf16(a.z, a.w);
  r.z = cvt_pk_bf16(b.x, b.y);
  r.w = cvt_pk_bf16(b.z, b.w);
  return r;
}

__device__ __forceinline__ bf16x8 ldfrag(const unsigned char* base, int row, int kbyte){
  return *reinterpret_cast<const bf16x8*>(base + row*128 + SWZ(row, kbyte));
}

// async global->LDS, 16B/lane; LDS dest linear, source pre-swizzled
__device__ __forceinline__ void gl_lds16(const void* g, void* l){
  __builtin_amdgcn_global_load_lds(
      (const __attribute__((address_space(1))) unsigned int*)g,
      (__attribute__((address_space(3))) unsigned int*)l, 16, 0, 0);
}

// ---------------- K1: per-head QKV projection + xnorm(v); emits qp, kp, kpT, vnT ----------------
// blockIdx.y >= H_: weight-conversion slabs.
__device__ __forceinline__ void proj_mfma(const unsigned char* X, const unsigned char* W,
                                          int wid, int l15, int g4, f32x4 acc[4])
{
  f32x4 z = {0.f,0.f,0.f,0.f};
  acc[0]=z; acc[1]=z; acc[2]=z; acc[3]=z;
  #pragma unroll
  for (int kk=0;kk<2;++kk){
    int kbyte = kk*64 + g4*16;
    bf16x8 a = ldfrag(X, wid*16 + l15, kbyte);
    #pragma unroll
    for (int t=0;t<4;++t){
      bf16x8 w = ldfrag(W, t*16 + l15, kbyte);
      acc[t] = __builtin_amdgcn_mfma_f32_16x16x32_bf16(a, w, acc[t], 0, 0, 0);
    }
  }
}

__global__ __launch_bounds__(256) void k_proj(
    const float* __restrict__ qin, const float* __restrict__ kin, const float* __restrict__ vin,
    const float* __restrict__ Wq, const float* __restrict__ Wk, const float* __restrict__ Wv,
    u16* __restrict__ qp, u16* __restrict__ kp, u16* __restrict__ kpT, u16* __restrict__ vnT,
    const float* __restrict__ Wo, const float* __restrict__ Wsq,
    u16* __restrict__ wo16, u16* __restrict__ wsq16)
{
  __shared__ alignas(16) unsigned char sm[49152];
  if (blockIdx.y >= H_){
    int cblk = (blockIdx.y - H_)*64 + blockIdx.x;
    int n4 = (E_*E_)/4;
    for (int i = cblk*256 + threadIdx.x; i < 2*n4; i += 128*256){
      const float4* src; ushort4* dst; int j;
      if (i < n4){ src=(const float4*)Wo;  dst=(ushort4*)wo16;  j=i; }
      else       { src=(const float4*)Wsq; dst=(ushort4*)wsq16; j=i-n4; }
      float4 v = src[j];
      ushort4 p; p.x=f2bf(v.x); p.y=f2bf(v.y); p.z=f2bf(v.z); p.w=f2bf(v.w);
      dst[j] = p;
    }
    return;
  }
  const int XQ=0, XK=8192, XV=16384, WQS=24576, WKS=32768, WVS=40960;
  int tid = threadIdx.x, lane = tid&63, wid = tid>>6;
  int l15 = lane&15, g4 = lane>>4;
  int tb = blockIdx.x*64;
  int h  = blockIdx.y;
  int b  = tb >> 11;
  int sbase = tb & 2047;
  int bh = b*H_ + h;

  { // stage X tiles and W tiles, fp32 -> bf16 via cvt_pk
    int rl = tid>>2;
    int d0 = (tid&3)*16;
    const float* xs[3] = { qin, kin, vin };
    const float* wsrc[3] = { Wq, Wk, Wv };
    const int xoff[3] = {XQ,XK,XV}, woff[3] = {WQS,WKS,WVS};
    #pragma unroll
    for (int m3=0;m3<3;++m3){
      const float4* gx = reinterpret_cast<const float4*>(xs[m3] + (size_t)(tb+rl)*E_ + h*HD_ + d0);
      float4 a=gx[0], bb=gx[1], c=gx[2], d=gx[3];
      *(uint4*)(sm + xoff[m3] + rl*128 + SWZ(rl, d0*2))    = pack8(a,bb);
      *(uint4*)(sm + xoff[m3] + rl*128 + SWZ(rl, d0*2+16)) = pack8(c,d);
      const float4* gw = reinterpret_cast<const float4*>(wsrc[m3] + rl*64 + d0);
      float4 e=gw[0], f=gw[1], g2=gw[2], h2=gw[3];
      *(uint4*)(sm + woff[m3] + rl*128 + SWZ(rl, d0*2))    = pack8(e,f);
      *(uint4*)(sm + woff[m3] + rl*128 + SWZ(rl, d0*2+16)) = pack8(g2,h2);
    }
  }
  __syncthreads();

  f32x4 qacc[4], kacc[4], vacc[4];
  proj_mfma(sm+XQ, sm+WQS, wid, l15, g4, qacc);
  proj_mfma(sm+XK, sm+WKS, wid, l15, g4, kacc);
  proj_mfma(sm+XV, sm+WVS, wid, l15, g4, vacc);

  {
    float p4r[4] = {0.f,0.f,0.f,0.f};
    #pragma unroll
    for (int t=0;t<4;++t)
      #pragma unroll
      for (int r=0;r<4;++r){ float e = vacc[t][r]; float e2 = e*e; p4r[r] += e2*e2; }
    #pragma unroll
    for (int r=0;r<4;++r){
      float p = p4r[r];
      p += __shfl_xor(p,1); p += __shfl_xor(p,2); p += __shfl_xor(p,4); p += __shfl_xor(p,8);
      p4r[r] = GAMMA / sqrtf(sqrtf(p));
    }
    #pragma unroll
    for (int t=0;t<4;++t)
      #pragma unroll
      for (int r=0;r<4;++r) vacc[t][r] *= p4r[r];
  }

  __syncthreads();   // X/W dead; reuse XQ/XK/XV/WQS as output staging

  #pragma unroll
  for (int t=0;t<4;++t){
    int dd = t*16 + l15;
    #pragma unroll
    for (int r=0;r<4;++r){
      int tokl = wid*16 + g4*4 + r;
      *(u16*)(sm + XQ + tokl*128 + SWZ(tokl, dd*2)) = f2bf(qacc[t][r]);
      *(u16*)(sm + XK + tokl*128 + SWZ(tokl, dd*2)) = f2bf(kacc[t][r]);
    }
    #pragma unroll
    for (int r=0;r<4;r+=2){
      int tokl = wid*16 + g4*4 + r;
      *(u32*)(sm + XV  + dd*128 + SWZ(dd, tokl*2)) = cvt_pk_bf16(vacc[t][r], vacc[t][r+1]);
      *(u32*)(sm + WQS + dd*128 + SWZ(dd, tokl*2)) = cvt_pk_bf16(kacc[t][r], kacc[t][r+1]);
    }
  }
  __syncthreads();

  {
    int rl = tid>>2; int c2 = tid&3;
    uint4 q0 = *(const uint4*)(sm + XQ + rl*128 + SWZ(rl, c2*32));
    uint4 q1 = *(const uint4*)(sm + XQ + rl*128 + SWZ(rl, c2*32+16));
    size_t qg = ((size_t)bh*S_ + sbase + rl)*HD_ + c2*16;
    *(uint4*)(qp + qg)     = q0;
    *(uint4*)(qp + qg + 8) = q1;
    uint4 k0 = *(const uint4*)(sm + XK + rl*128 + SWZ(rl, c2*32));
    uint4 k1 = *(const uint4*)(sm + XK + rl*128 + SWZ(rl, c2*32+16));
    *(uint4*)(kp + qg)     = k0;
    *(uint4*)(kp + qg + 8) = k1;
    size_t vg = ((size_t)bh*HD_ + rl)*S_ + sbase + c2*16;
    uint4 v0 = *(const uint4*)(sm + XV + rl*128 + SWZ(rl, c2*32));
    uint4 v1 = *(const uint4*)(sm + XV + rl*128 + SWZ(rl, c2*32+16));
    *(uint4*)(vnT + vg)     = v0;
    *(uint4*)(vnT + vg + 8) = v1;
    uint4 t0 = *(const uint4*)(sm + WQS + rl*128 + SWZ(rl, c2*32));
    uint4 t1 = *(const uint4*)(sm + WQS + rl*128 + SWZ(rl, c2*32+16));
    *(uint4*)(kpT + vg)     = t0;
    *(uint4*)(kpT + vg + 8) = t1;
  }
}

// ---------------- K2a: MT[bh][e][d] = sum_s Vn[s][e] * K[s][d]   (Kt Vn factor) ----------------
// One block per bh; 4 waves split s (512 each); cross-wave reduce in LDS; wave 0
// transposes to row-major bf16 via LDS and stores 8KB.
__global__ __launch_bounds__(256) void k_kv(
    const u16* __restrict__ kpT, const u16* __restrict__ vnT, u16* __restrict__ MT)
{
  __shared__ alignas(128) unsigned char sm[32768];
  char* smc = (char*)sm;
  int tid = threadIdx.x, lane = tid&63, wv = tid>>6;
  int l31 = lane&31, hi = lane>>5;
  int bh = blockIdx.x;
  const u16* kt = kpT + (size_t)bh*HD_*S_;
  const u16* vt = vnT + (size_t)bh*HD_*S_;

  f32x16 acc[2][2] = {{{}, {}}, {{}, {}}};   // [eh][dh]: MT[e=eh*32+l31][d=dh*32+crow]
  int sbase = wv*512 + hi*8;

  #pragma unroll 2
  for (int it=0; it<32; ++it){
    int so = sbase + it*16;
    bf16x8 ka0 = *reinterpret_cast<const bf16x8*>(kt + (size_t)l31*S_      + so);
    bf16x8 ka1 = *reinterpret_cast<const bf16x8*>(kt + (size_t)(32+l31)*S_ + so);
    bf16x8 vb0 = *reinterpret_cast<const bf16x8*>(vt + (size_t)l31*S_      + so);
    bf16x8 vb1 = *reinterpret_cast<const bf16x8*>(vt + (size_t)(32+l31)*S_ + so);
    acc[0][0] = __builtin_amdgcn_mfma_f32_32x32x16_bf16(ka0, vb0, acc[0][0], 0,0,0);
    acc[0][1] = __builtin_amdgcn_mfma_f32_32x32x16_bf16(ka1, vb0, acc[0][1], 0,0,0);
    acc[1][0] = __builtin_amdgcn_mfma_f32_32x32x16_bf16(ka0, vb1, acc[1][0], 0,0,0);
    acc[1][1] = __builtin_amdgcn_mfma_f32_32x32x16_bf16(ka1, vb1, acc[1][1], 0,0,0);
  }

  auto wrAcc = [&](int sl){
    float* base = (float*)(smc + sl*16384);
    #pragma unroll
    for (int eh=0;eh<2;++eh)
      #pragma unroll
      for (int dh=0;dh<2;++dh){
        float* dst = base + (((eh*2+dh)*64 + lane)*16);
        #pragma unroll
        for (int r4=0;r4<4;++r4)
          *(float4*)(dst + r4*4) = make_float4(acc[eh][dh][r4*4],acc[eh][dh][r4*4+1],
                                               acc[eh][dh][r4*4+2],acc[eh][dh][r4*4+3]);
      }
  };
  auto addAcc = [&](int sl){
    const float* base = (const float*)(smc + sl*16384);
    #pragma unroll
    for (int eh=0;eh<2;++eh)
      #pragma unroll
      for (int dh=0;dh<2;++dh){
        const float* srcp = base + (((eh*2+dh)*64 + lane)*16);
        #pragma unroll
        for (int r4=0;r4<4;++r4){
          float4 t = *(const float4*)(srcp + r4*4);
          acc[eh][dh][r4*4]+=t.x; acc[eh][dh][r4*4+1]+=t.y;
          acc[eh][dh][r4*4+2]+=t.z; acc[eh][dh][r4*4+3]+=t.w;
        }
      }
  };

  if (wv==1) wrAcc(0);
  if (wv==3) wrAcc(1);
  __syncthreads();
  if (wv==0) addAcc(0);
  if (wv==2) addAcc(1);
  __syncthreads();
  if (wv==2) wrAcc(0);
  __syncthreads();
  if (wv==0) addAcc(0);
  __syncthreads();
  if (wv==0){   // transpose to row-major [e][d] bf16 via LDS
    #pragma unroll
    for (int eh=0;eh<2;++eh)
      #pragma unroll
      for (int dh=0;dh<2;++dh)
        #pragma unroll
        for (int r=0;r<16;r+=2){
          int e = eh*32 + l31;
          int d = dh*32 + (r&3) + 8*(r>>2) + 4*hi;
          *(u32*)(smc + e*128 + SWZ(e, d*2)) = cvt_pk_bf16(acc[eh][dh][r], acc[eh][dh][r+1]);
        }
  }
  __syncthreads();
  if (wv==0){
    u16* dst = MT + (size_t)bh*4096 + lane*64;
    #pragma unroll
    for (int c=0;c<8;++c)
      *(uint4*)(dst + c*8) = *(const uint4*)(smc + lane*128 + SWZ(lane, c*16));
  }
}

// ---------------- K2b: attention = QK^T -> p4 only; out = Q @ MT, scaled ----------------
// Block: 128 q, 4 waves (2qi x 2kj). Per 128-key tile: K-only staging (3x16KB,
// one barrier, vmcnt(4)), 16 QK MFMAs + e^4 accumulation per wave. No V, no E
// materialization. Epilogue: p4 cross-kj reduce, 8-MFMA out-GEMM vs MT, LDS
// transpose, coalesced store.
__global__ __launch_bounds__(256, 2) void k_attn(
    const u16* __restrict__ qp, const u16* __restrict__ kp,
    const u16* __restrict__ MT, u16* __restrict__ ao)
{
  __shared__ alignas(128) unsigned char sm[49152];   // K: 3 x 16KB; reused by epilogue
  __shared__ float px[256];
  char* smc = (char*)sm;
  int tid = threadIdx.x, lane = tid&63, wv = tid>>6;
  int l31 = lane&31, hi = lane>>5;
  int qi = wv>>1, kj = wv&1;
  int L = blockIdx.x;
  int xcd = L&7, iw = L>>3;            // iw 0..63
  int bh = xcd*4 + (iw>>4);            // consecutive iw share bh (L1/L2 reuse)
  int qx = iw&15;
  int qb = qx*128;
  int b = bh>>4, h = bh&15;
  const u16* Kb = kp + (size_t)bh*S_*HD_;
  const u16* Qb = qp + (size_t)bh*S_*HD_;
  int q0 = qb + qi*64;

  bf16x8 qf[2][4];
  #pragma unroll
  for (int f=0;f<2;++f)
    #pragma unroll
    for (int kk=0;kk<4;++kk)
      qf[f][kk] = *reinterpret_cast<const bf16x8*>(Qb + (size_t)(q0 + f*32 + l31)*HD_ + kk*16 + hi*8);

  f32x16 z16 = {};
  f32x2 p4a[2] = {{0.f,0.f},{0.f,0.f}};
  f32x2 p4b[2] = {{0.f,0.f},{0.f,0.f}};

  const char* kSrcC[4];
  #pragma unroll
  for (int c=0;c<4;++c){
    int rk = wv*32 + c*8 + (lane>>3);
    int ck = ((lane&7)*16) ^ ((rk&7)<<4);
    kSrcC[c] = (const char*)Kb + (size_t)rk*128 + ck;
  }

  auto STAGE_K = [&](int bsel, int kt){
    char* db = smc + bsel*16384 + wv*4096;
    #pragma unroll
    for (int c=0;c<4;++c) gl_lds16(kSrcC[c] + (size_t)kt*16384, db + c*1024);
  };

  // e^4 accumulation with packed f32 math
  auto P4ACC = [&](const f32x16& e, f32x2& pa){
    #pragma unroll
    for (int j=0;j<8;++j){
      f32x2 pr = {e[2*j], e[2*j+1]};
      f32x2 e2;
      asm("v_pk_mul_f32 %0, %1, %1" : "=v"(e2) : "v"(pr));
      asm("v_pk_fma_f32 %0, %1, %1, %0" : "+v"(pa) : "v"(e2));
    }
  };

  auto QK = [&](const unsigned char* K_, int s2, f32x16& E0, f32x16& E1){
    bf16x8 ka[4];
    #pragma unroll
    for (int kk=0;kk<4;++kk) ka[kk] = ldfrag(K_, kj*64 + s2*32 + l31, kk*32 + hi*16);
    E0 = z16; E1 = z16;
    __builtin_amdgcn_s_setprio(1);
    #pragma unroll
    for (int kk=0;kk<4;++kk){
      E0 = __builtin_amdgcn_mfma_f32_32x32x16_bf16(ka[kk], qf[0][kk], E0, 0,0,0);
      E1 = __builtin_amdgcn_mfma_f32_32x32x16_bf16(ka[kk], qf[1][kk], E1, 0,0,0);
    }
    __builtin_amdgcn_s_setprio(0);
  };

  const int NT = S_/128;   // 16
  STAGE_K(0, 0); STAGE_K(1, 1);

  f32x16 eA0, eA1, eB0, eB1;

  #pragma unroll 1
  for (int t=0; t<NT; ++t){
    if (t < NT-1) { asm volatile("s_waitcnt vmcnt(4)" ::: "memory"); }
    else          { asm volatile("s_waitcnt vmcnt(0)" ::: "memory"); }
    __builtin_amdgcn_s_barrier();
    asm volatile("" ::: "memory");
    if (t+2 < NT) STAGE_K((t+2)%3, t+2);

    const unsigned char* K_ = sm + (t%3)*16384;
    QK(K_, 0, eA0, eA1);
    QK(K_, 1, eB0, eB1);
    P4ACC(eA0, p4a[0]);
    P4ACC(eA1, p4a[1]);
    P4ACC(eB0, p4b[0]);
    P4ACC(eB1, p4b[1]);
  }

  // ---- p4 totals (this wave's key half), then cross-kj exchange ----
  float p4f[2];
  #pragma unroll
  for (int f=0;f<2;++f){
    p4f[f] = p4a[f].x + p4a[f].y + p4b[f].x + p4b[f].y;
    p4f[f] += __shfl_xor(p4f[f], 32);
  }
  __syncthreads();                      // all K-buffer reads done
  if (hi==0){
    px[((qi*2+0)*2+kj)*32 + l31] = p4f[0];
    px[((qi*2+1)*2+kj)*32 + l31] = p4f[1];
  }
  __syncthreads();
  #pragma unroll
  for (int f=0;f<2;++f) p4f[f] += px[((qi*2+f)*2+(1-kj))*32 + l31];
  float sc0 = GAMMA * rsqrtf(sqrtf(p4f[0]));
  float sc1 = GAMMA * rsqrtf(sqrtf(p4f[1]));

  // ---- out = Q @ MT  (wave covers e-half kj*32..+31 for its 64 q-rows) ----
  const u16* mtb = MT + (size_t)bh*4096;
  bf16x8 mtf[4];
  #pragma unroll
  for (int kk=0;kk<4;++kk)
    mtf[kk] = *reinterpret_cast<const bf16x8*>(mtb + (kj*32 + l31)*64 + kk*16 + hi*8);
  f32x16 oA0 = z16, oA1 = z16;
  #pragma unroll
  for (int kk=0;kk<4;++kk){
    oA0 = __builtin_amdgcn_mfma_f32_32x32x16_bf16(mtf[kk], qf[0][kk], oA0, 0,0,0);
    oA1 = __builtin_amdgcn_mfma_f32_32x32x16_bf16(mtf[kk], qf[1][kk], oA1, 0,0,0);
  }

  // ---- scale + LDS transpose + coalesced store ----
  __syncthreads();                      // px reads done; reuse smc for out tile [128][64]
  #pragma unroll
  for (int r=0;r<16;r+=2){
    int e = kj*32 + (r&3) + 8*(r>>2) + 4*hi;
    int ql0 = qi*64 + l31;
    *(u32*)(smc + ql0*128 + SWZ(ql0, e*2))         = cvt_pk_bf16(oA0[r]*sc0, oA0[r+1]*sc0);
    int ql1 = qi*64 + 32 + l31;
    *(u32*)(smc + ql1*128 + SWZ(ql1, e*2))         = cvt_pk_bf16(oA1[r]*sc1, oA1[r+1]*sc1);
  }
  __syncthreads();
  {
    int row = tid>>1, eh = tid&1;
    u16* dst = ao + ((size_t)b*S_ + qb + row)*E_ + h*HD_ + eh*32;
    #pragma unroll
    for (int c=0;c<4;++c)
      *(uint4*)(dst + c*8) = *(const uint4*)(smc + row*128 + SWZ(row, eh*64 + c*16));
  }
}

// ---------------- K3/K5: 128x128-tile bf16 GEMM, 64x64 per wave ----------------
template<int MODE>
__global__ __launch_bounds__(256, 2) void k_gemm(
    const u16* __restrict__ A, const u16* __restrict__ Bw,
    const float* __restrict__ bias, const float* __restrict__ auxf,
    const u16* __restrict__ aux16, float* __restrict__ out32, u16* __restrict__ out16)
{
  __shared__ alignas(128) unsigned char sm[65536];   // 2 x (A 16KB + B 16KB)
  char* smc = (char*)sm;
  int tid = threadIdx.x, lane = tid&63, wv = tid>>6;
  int l31 = lane&31, hi = lane>>5;
  int wr = wv>>1, wc = wv&1;
  int LL = (blockIdx.x & 7)*32 + (blockIdx.x >> 3);
  int mt = LL >> 3, nt = LL & 7;                      // 32 m-tiles x 8 n-tiles
  int m0 = mt*128, n0 = nt*128;

  const char* aS[4]; const char* bS[4];
  #pragma unroll
  for (int c=0;c<4;++c){
    int off = wv*4096 + c*1024 + lane*16;
    int r = off>>7, cl = off&127;
    int cs = cl ^ ((r&7)<<4);
    aS[c] = (const char*)A  + ((size_t)(m0+r)*E_)*2 + cs;
    bS[c] = (const char*)Bw + ((size_t)(n0+r)*E_)*2 + cs;
  }

  auto STAGE = [&](int bsel, int t){
    char* db = smc + bsel*32768 + wv*4096;
    size_t kb2 = (size_t)t*128;
    #pragma unroll
    for (int c=0;c<4;++c) gl_lds16(aS[c] + kb2, db + c*1024);
    #pragma unroll
    for (int c=0;c<4;++c) gl_lds16(bS[c] + kb2, db + 16384 + c*1024);
  };

  f32x16 acc[2][2] = {{{}, {}}, {{}, {}}};

  const int NK = E_/64;   // 16
  STAGE(0, 0); STAGE(1, 1);

  #pragma unroll 1
  for (int t=0; t<NK; ++t){
    if (t < NK-1) { asm volatile("s_waitcnt vmcnt(8)" ::: "memory"); }
    else          { asm volatile("s_waitcnt vmcnt(0)" ::: "memory"); }
    __builtin_amdgcn_s_barrier();
    asm volatile("" ::: "memory");

    const unsigned char* Ap_ = sm + (t&1)*32768;
    const unsigned char* Bp_ = Ap_ + 16384;
    #pragma unroll
    for (int kk=0;kk<4;++kk){
      int kbyte = kk*32 + hi*16;
      bf16x8 a0 = ldfrag(Ap_, wr*64 + l31,      kbyte);
      bf16x8 a1 = ldfrag(Ap_, wr*64 + 32 + l31, kbyte);
      bf16x8 b0 = ldfrag(Bp_, wc*64 + l31,      kbyte);
      bf16x8 b1 = ldfrag(Bp_, wc*64 + 32 + l31, kbyte);
      __builtin_amdgcn_s_setprio(1);
      acc[0][0] = __builtin_amdgcn_mfma_f32_32x32x16_bf16(a0, b0, acc[0][0], 0,0,0);
      acc[0][1] = __builtin_amdgcn_mfma_f32_32x32x16_bf16(a0, b1, acc[0][1], 0,0,0);
      acc[1][0] = __builtin_amdgcn_mfma_f32_32x32x16_bf16(a1, b0, acc[1][0], 0,0,0);
      acc[1][1] = __builtin_amdgcn_mfma_f32_32x32x16_bf16(a1, b1, acc[1][1], 0,0,0);
      __builtin_amdgcn_s_setprio(0);
    }

    asm volatile("" ::: "memory");
    __builtin_amdgcn_s_barrier();
    asm volatile("" ::: "memory");
    if (t+2 < NK) STAGE(t&1, t+2);
  }

  #pragma unroll
  for (int cg=0;cg<2;++cg){
    int col = n0 + wc*64 + cg*32 + l31;
    float bi = bias[col];
    #pragma unroll
    for (int rg=0;rg<2;++rg)
      #pragma unroll
      for (int r=0;r<16;++r){
        int mrow = m0 + wr*64 + rg*32 + (r&3) + 8*(r>>2) + 4*hi;
        size_t idx = (size_t)mrow*E_ + col;
        float v = acc[rg][cg][r] + bi;
        if (MODE == 0){
          out16[idx] = f2bf(v + auxf[idx]);
        } else {
          float gg = 1.f/(1.f + __expf(-v));
          out32[idx] = bf2f(aux16[idx]) * gg;
        }
      }
  }
}

// ---------------- K4: LayerNorm over embed dim; bf16 in -> bf16 out ----------------
__global__ __launch_bounds__(256) void k_ln(
    const u16* __restrict__ xin, const float* __restrict__ lnw, const float* __restrict__ lnb,
    u16* __restrict__ xout)
{
  __shared__ float red[8];
  __shared__ float stats[2];
  int row = blockIdx.x, tid = threadIdx.x;
  ushort4 xr = reinterpret_cast<const ushort4*>(xin + (size_t)row*E_)[tid];
  float x0 = bf2f(xr.x), x1 = bf2f(xr.y), x2 = bf2f(xr.z), x3 = bf2f(xr.w);
  float s  = x0 + x1 + x2 + x3;
  float s2 = x0*x0 + x1*x1 + x2*x2 + x3*x3;
  #pragma unroll
  for (int m=1;m<64;m<<=1){ s += __shfl_xor(s,m); s2 += __shfl_xor(s2,m); }
  if ((tid&63)==0){ red[tid>>6] = s; red[4+(tid>>6)] = s2; }
  __syncthreads();
  if (tid==0){
    float ts  = red[0]+red[1]+red[2]+red[3];
    float ts2 = red[4]+red[5]+red[6]+red[7];
    float mu  = ts * (1.f/E_);
    float var = ts2 * (1.f/E_) - mu*mu;
    stats[0] = mu; stats[1] = rsqrtf(var + 1e-5f);
  }
  __syncthreads();
  float mu = stats[0], rstd = stats[1];
  float4 w  = reinterpret_cast<const float4*>(lnw)[tid];
  float4 bb = reinterpret_cast<const float4*>(lnb)[tid];
  ushort4 p;
  p.x = f2bf((x0-mu)*rstd*w.x + bb.x);
  p.y = f2bf((x1-mu)*rstd*w.y + bb.y);
  p.z = f2bf((x2-mu)*rstd*w.z + bb.z);
  p.w = f2bf((x3-mu)*rstd*w.w + bb.w);
  reinterpret_cast<ushort4*>(xout + (size_t)row*E_)[tid] = p;
}

// ---------------- host launch ----------------
extern "C" void kernel_launch(void* const* d_in, const int* in_sizes, int n_in,
                              void* d_out, int out_size, void* d_ws, size_t ws_size,
                              hipStream_t stream)
{
  const float* value = (const float*)d_in[0];
  const float* key   = (const float*)d_in[1];
  const float* query = (const float*)d_in[2];
  const float* Wq    = (const float*)d_in[3];
  const float* Wk    = (const float*)d_in[4];
  const float* Wv    = (const float*)d_in[5];
  const float* Wo    = (const float*)d_in[6];
  const float* bo    = (const float*)d_in[7];
  const float* lnw   = (const float*)d_in[8];
  const float* lnb   = (const float*)d_in[9];
  const float* Wsq   = (const float*)d_in[10];
  const float* bsq   = (const float*)d_in[11];
  float* out = (float*)d_out;

  char* ws = (char*)d_ws;
  const size_t MB = 1ull<<20;
  u16*   qp     = (u16*)(ws + 0*MB);    // K1->K2
  u16*   kp     = (u16*)(ws + 8*MB);    // K1->K2b
  u16*   vnT    = (u16*)(ws + 16*MB);   // K1->K2a
  u16*   kpT    = (u16*)(ws + 24*MB);   // K1->K2a
  u16*   ao     = (u16*)(ws + 32*MB);   // K2b->K3 (8MB)
  u16*   mtw    = (u16*)(ws + 44*MB);   // K2a->K2b (256KB)
  u16*   xres16 = (u16*)(ws + 8*MB);    // K3->K4 (over kp, dead after attn)
  u16*   x16    = (u16*)(ws + 16*MB);   // K4->K5 (over vnT, dead after k_kv)
  u16*   wo16   = (u16*)(ws + 48*MB);
  u16*   wsq16  = (u16*)(ws + 50*MB);

  k_proj<<<dim3(N_/64, H_+2), 256, 0, stream>>>(query, key, value, Wq, Wk, Wv,
                                                qp, kp, kpT, vnT, Wo, Wsq, wo16, wsq16);
  k_kv  <<<BH_, 256, 0, stream>>>(kpT, vnT, mtw);
  k_attn<<<512, 256, 0, stream>>>(qp, kp, mtw, ao);
  k_gemm<0><<<256, 256, 0, stream>>>(ao, wo16, bo, query, (const u16*)nullptr, (float*)nullptr, xres16);
  k_ln  <<<N_, 256, 0, stream>>>(xres16, lnw, lnb, x16);
  k_gemm<1><<<256, 256, 0, stream>>>(x16, wsq16, bsq, (const float*)nullptr, x16, out, (u16*)nullptr);
}

// Round 16
// 111.091 us; speedup vs baseline: 1.0066x; 1.0066x over previous
//
#include <hip/hip_runtime.h>
#include <stdint.h>

#define B_ 2
#define S_ 2048
#define E_ 1024
#define H_ 16
#define HD_ 64
#define N_ (B_*S_)
#define BH_ (B_*H_)
#define GAMMA 0.01f

typedef __attribute__((ext_vector_type(8))) short bf16x8;
typedef __attribute__((ext_vector_type(4))) float f32x4;
typedef __attribute__((ext_vector_type(2))) float f32x2;
typedef __attribute__((ext_vector_type(16))) float f32x16;
typedef unsigned short u16;
typedef unsigned int u32;

// byte-level XOR swizzle within a 128B row
#define SWZ(row, kb) ((kb) ^ (((row)&7)<<4))

__device__ __forceinline__ u16 f2bf(float f){
  union { float f; u32 u; } v; v.f = f;
  return (u16)((v.u + 0x7FFFu + ((v.u>>16)&1u)) >> 16);
}

__device__ __forceinline__ float bf2f(u16 u){
  union { u32 u; float f; } v; v.u = ((u32)u)<<16; return v.f;
}

__device__ __forceinline__ u32 cvt_pk_bf16(float lo, float hi){
  u32 r; asm("v_cvt_pk_bf16_f32 %0, %1, %2" : "=v"(r) : "v"(lo), "v"(hi)); return r;
}

__device__ __forceinline__ uint4 pack8(float4 a, float4 b){
  uint4 r;
  r.x = cvt_pk_bf16(a.x, a.y);
  r.y = cvt_pk_bf16(a.z, a.w);
  r.z = cvt_pk_bf16(b.x, b.y);
  r.w = cvt_pk_bf16(b.z, b.w);
  return r;
}

__device__ __forceinline__ bf16x8 ldfrag(const unsigned char* base, int row, int kbyte){
  return *reinterpret_cast<const bf16x8*>(base + row*128 + SWZ(row, kbyte));
}

// async global->LDS, 16B/lane; LDS dest linear, source pre-swizzled
__device__ __forceinline__ void gl_lds16(const void* g, void* l){
  __builtin_amdgcn_global_load_lds(
      (const __attribute__((address_space(1))) unsigned int*)g,
      (__attribute__((address_space(3))) unsigned int*)l, 16, 0, 0);
}

// ---------------- K1: per-head QKV projection + xnorm(v); emits qp, kp, kpT, vnT ----------------
__device__ __forceinline__ void proj_mfma(const unsigned char* X, const unsigned char* W,
                                          int wid, int l15, int g4, f32x4 acc[4])
{
  f32x4 z = {0.f,0.f,0.f,0.f};
  acc[0]=z; acc[1]=z; acc[2]=z; acc[3]=z;
  #pragma unroll
  for (int kk=0;kk<2;++kk){
    int kbyte = kk*64 + g4*16;
    bf16x8 a = ldfrag(X, wid*16 + l15, kbyte);
    #pragma unroll
    for (int t=0;t<4;++t){
      bf16x8 w = ldfrag(W, t*16 + l15, kbyte);
      acc[t] = __builtin_amdgcn_mfma_f32_16x16x32_bf16(a, w, acc[t], 0, 0, 0);
    }
  }
}

__global__ __launch_bounds__(256) void k_proj(
    const float* __restrict__ qin, const float* __restrict__ kin, const float* __restrict__ vin,
    const float* __restrict__ Wq, const float* __restrict__ Wk, const float* __restrict__ Wv,
    u16* __restrict__ qp, u16* __restrict__ kp, u16* __restrict__ kpT, u16* __restrict__ vnT,
    const float* __restrict__ Wo, const float* __restrict__ Wsq,
    u16* __restrict__ wo16, u16* __restrict__ wsq16)
{
  __shared__ alignas(16) unsigned char sm[49152];
  if (blockIdx.y >= H_){
    int cblk = (blockIdx.y - H_)*64 + blockIdx.x;
    int n4 = (E_*E_)/4;
    for (int i = cblk*256 + threadIdx.x; i < 2*n4; i += 128*256){
      const float4* src; ushort4* dst; int j;
      if (i < n4){ src=(const float4*)Wo;  dst=(ushort4*)wo16;  j=i; }
      else       { src=(const float4*)Wsq; dst=(ushort4*)wsq16; j=i-n4; }
      float4 v = src[j];
      ushort4 p; p.x=f2bf(v.x); p.y=f2bf(v.y); p.z=f2bf(v.z); p.w=f2bf(v.w);
      dst[j] = p;
    }
    return;
  }
  const int XQ=0, XK=8192, XV=16384, WQS=24576, WKS=32768, WVS=40960;
  int tid = threadIdx.x, lane = tid&63, wid = tid>>6;
  int l15 = lane&15, g4 = lane>>4;
  int tb = blockIdx.x*64;
  int h  = blockIdx.y;
  int b  = tb >> 11;
  int sbase = tb & 2047;
  int bh = b*H_ + h;

  {
    int rl = tid>>2;
    int d0 = (tid&3)*16;
    const float* xs[3] = { qin, kin, vin };
    const float* wsrc[3] = { Wq, Wk, Wv };
    const int xoff[3] = {XQ,XK,XV}, woff[3] = {WQS,WKS,WVS};
    #pragma unroll
    for (int m3=0;m3<3;++m3){
      const float4* gx = reinterpret_cast<const float4*>(xs[m3] + (size_t)(tb+rl)*E_ + h*HD_ + d0);
      float4 a=gx[0], bb=gx[1], c=gx[2], d=gx[3];
      *(uint4*)(sm + xoff[m3] + rl*128 + SWZ(rl, d0*2))    = pack8(a,bb);
      *(uint4*)(sm + xoff[m3] + rl*128 + SWZ(rl, d0*2+16)) = pack8(c,d);
      const float4* gw = reinterpret_cast<const float4*>(wsrc[m3] + rl*64 + d0);
      float4 e=gw[0], f=gw[1], g2=gw[2], h2=gw[3];
      *(uint4*)(sm + woff[m3] + rl*128 + SWZ(rl, d0*2))    = pack8(e,f);
      *(uint4*)(sm + woff[m3] + rl*128 + SWZ(rl, d0*2+16)) = pack8(g2,h2);
    }
  }
  __syncthreads();

  f32x4 qacc[4], kacc[4], vacc[4];
  proj_mfma(sm+XQ, sm+WQS, wid, l15, g4, qacc);
  proj_mfma(sm+XK, sm+WKS, wid, l15, g4, kacc);
  proj_mfma(sm+XV, sm+WVS, wid, l15, g4, vacc);

  {
    float p4r[4] = {0.f,0.f,0.f,0.f};
    #pragma unroll
    for (int t=0;t<4;++t)
      #pragma unroll
      for (int r=0;r<4;++r){ float e = vacc[t][r]; float e2 = e*e; p4r[r] += e2*e2; }
    #pragma unroll
    for (int r=0;r<4;++r){
      float p = p4r[r];
      p += __shfl_xor(p,1); p += __shfl_xor(p,2); p += __shfl_xor(p,4); p += __shfl_xor(p,8);
      p4r[r] = GAMMA / sqrtf(sqrtf(p));
    }
    #pragma unroll
    for (int t=0;t<4;++t)
      #pragma unroll
      for (int r=0;r<4;++r) vacc[t][r] *= p4r[r];
  }

  __syncthreads();   // X/W dead; reuse XQ/XK/XV/WQS as output staging

  #pragma unroll
  for (int t=0;t<4;++t){
    int dd = t*16 + l15;
    #pragma unroll
    for (int r=0;r<4;++r){
      int tokl = wid*16 + g4*4 + r;
      *(u16*)(sm + XQ + tokl*128 + SWZ(tokl, dd*2)) = f2bf(qacc[t][r]);
      *(u16*)(sm + XK + tokl*128 + SWZ(tokl, dd*2)) = f2bf(kacc[t][r]);
    }
    #pragma unroll
    for (int r=0;r<4;r+=2){
      int tokl = wid*16 + g4*4 + r;
      *(u32*)(sm + XV  + dd*128 + SWZ(dd, tokl*2)) = cvt_pk_bf16(vacc[t][r], vacc[t][r+1]);
      *(u32*)(sm + WQS + dd*128 + SWZ(dd, tokl*2)) = cvt_pk_bf16(kacc[t][r], kacc[t][r+1]);
    }
  }
  __syncthreads();

  {
    int rl = tid>>2; int c2 = tid&3;
    uint4 q0 = *(const uint4*)(sm + XQ + rl*128 + SWZ(rl, c2*32));
    uint4 q1 = *(const uint4*)(sm + XQ + rl*128 + SWZ(rl, c2*32+16));
    size_t qg = ((size_t)bh*S_ + sbase + rl)*HD_ + c2*16;
    *(uint4*)(qp + qg)     = q0;
    *(uint4*)(qp + qg + 8) = q1;
    uint4 k0 = *(const uint4*)(sm + XK + rl*128 + SWZ(rl, c2*32));
    uint4 k1 = *(const uint4*)(sm + XK + rl*128 + SWZ(rl, c2*32+16));
    *(uint4*)(kp + qg)     = k0;
    *(uint4*)(kp + qg + 8) = k1;
    size_t vg = ((size_t)bh*HD_ + rl)*S_ + sbase + c2*16;
    uint4 v0 = *(const uint4*)(sm + XV + rl*128 + SWZ(rl, c2*32));
    uint4 v1 = *(const uint4*)(sm + XV + rl*128 + SWZ(rl, c2*32+16));
    *(uint4*)(vnT + vg)     = v0;
    *(uint4*)(vnT + vg + 8) = v1;
    uint4 t0 = *(const uint4*)(sm + WQS + rl*128 + SWZ(rl, c2*32));
    uint4 t1 = *(const uint4*)(sm + WQS + rl*128 + SWZ(rl, c2*32+16));
    *(uint4*)(kpT + vg)     = t0;
    *(uint4*)(kpT + vg + 8) = t1;
  }
}

// ---------------- K2a: partial MT = sum_{s in chunk} Vn[s][e]*K[s][d] ----------------
// Grid 256 = 32 bh x 8 s-chunks (1 block/CU). Coalesced LDS staging [64][512B]
// with 32-slot XOR swizzle; each wave MFMAs its 64-s quarter, dumps its raw
// D-layout fp32 partial (4KB floats) to scratch. k_kvr reduces.
__global__ __launch_bounds__(256) void k_kv(
    const u16* __restrict__ kpT, const u16* __restrict__ vnT, float* __restrict__ part)
{
  __shared__ alignas(128) unsigned char sm[65536];   // K 32KB + V 32KB
  char* smc = (char*)sm;
  int tid = threadIdx.x, lane = tid&63, wv = tid>>6;
  int l31 = lane&31, hi = lane>>5;
  int bh = blockIdx.x >> 3, ch = blockIdx.x & 7;
  const char* kt = (const char*)(kpT + (size_t)bh*HD_*S_ + ch*256);
  const char* vt = (const char*)(vnT + (size_t)bh*HD_*S_ + ch*256);

  // stage: wave wv covers rows wv*16..+15 (8 calls of 1KB each per matrix)
  #pragma unroll
  for (int c=0;c<8;++c){
    int off = wv*8192 + c*1024 + lane*16;
    int row = off>>9, sl = (off&511)>>4;
    int ssl = sl ^ (row&31);
    gl_lds16(kt + (size_t)row*S_*2 + ssl*16, smc + off);
    gl_lds16(vt + (size_t)row*S_*2 + ssl*16, smc + 32768 + off);
  }
  asm volatile("s_waitcnt vmcnt(0)" ::: "memory");
  __builtin_amdgcn_s_barrier();
  asm volatile("" ::: "memory");

  auto LD = [&](int mo, int row, int byte) -> bf16x8 {
    return *reinterpret_cast<const bf16x8*>(smc + mo + row*512 + (byte ^ ((row&31)<<4)));
  };

  f32x16 acc[2][2] = {{{}, {}}, {{}, {}}};   // [eh][dh]; D: row=d, col=e
  #pragma unroll
  for (int it=0; it<4; ++it){
    int kb = wv*128 + it*32 + hi*16;           // byte offset of this frag's s-slice
    bf16x8 ka0 = LD(0,     l31,    kb);
    bf16x8 ka1 = LD(0,     32+l31, kb);
    bf16x8 vb0 = LD(32768, l31,    kb);
    bf16x8 vb1 = LD(32768, 32+l31, kb);
    acc[0][0] = __builtin_amdgcn_mfma_f32_32x32x16_bf16(ka0, vb0, acc[0][0], 0,0,0);
    acc[0][1] = __builtin_amdgcn_mfma_f32_32x32x16_bf16(ka1, vb0, acc[0][1], 0,0,0);
    acc[1][0] = __builtin_amdgcn_mfma_f32_32x32x16_bf16(ka0, vb1, acc[1][0], 0,0,0);
    acc[1][1] = __builtin_amdgcn_mfma_f32_32x32x16_bf16(ka1, vb1, acc[1][1], 0,0,0);
  }

  // dump raw partial (layout-agnostic reduce downstream)
  float* dstw = part + ((size_t)blockIdx.x*4 + wv)*4096;
  #pragma unroll
  for (int eh=0;eh<2;++eh)
    #pragma unroll
    for (int dh=0;dh<2;++dh){
      float* d2 = dstw + ((eh*2+dh)*64 + lane)*16;
      #pragma unroll
      for (int r4=0;r4<4;++r4)
        *(float4*)(d2 + r4*4) = make_float4(acc[eh][dh][r4*4],acc[eh][dh][r4*4+1],
                                            acc[eh][dh][r4*4+2],acc[eh][dh][r4*4+3]);
    }
}

// ---------------- K2a': reduce 32 partials per bh, emit row-major bf16 MT ----------------
__global__ __launch_bounds__(256) void k_kvr(
    const float* __restrict__ part, u16* __restrict__ MT)
{
  int tid = threadIdx.x, lane = tid&63, quad = tid>>6;
  int l31 = lane&31, hi = lane>>5;
  int bh = blockIdx.x;
  float s[16] = {0,0,0,0,0,0,0,0,0,0,0,0,0,0,0,0};
  #pragma unroll 4
  for (int p=0;p<32;++p){
    const float* src = part + ((size_t)(bh*8 + (p>>2))*4 + (p&3))*4096 + (quad*64 + lane)*16;
    #pragma unroll
    for (int r4=0;r4<4;++r4){
      float4 t = *(const float4*)(src + r4*4);
      s[r4*4]+=t.x; s[r4*4+1]+=t.y; s[r4*4+2]+=t.z; s[r4*4+3]+=t.w;
    }
  }
  int eh = quad>>1, dh = quad&1;
  int e = eh*32 + l31;
  u16* dst = MT + (size_t)bh*4096 + e*64;
  #pragma unroll
  for (int r=0;r<16;r+=2){
    int d = dh*32 + (r&3) + 8*(r>>2) + 4*hi;
    *(u32*)(dst + d) = cvt_pk_bf16(s[r], s[r+1]);
  }
}

// ---------------- K2b: attention = QK^T -> p4 only; out = Q @ MT, scaled ----------------
__global__ __launch_bounds__(256, 2) void k_attn(
    const u16* __restrict__ qp, const u16* __restrict__ kp,
    const u16* __restrict__ MT, u16* __restrict__ ao)
{
  __shared__ alignas(128) unsigned char sm[49152];   // K: 3 x 16KB; reused by epilogue
  __shared__ float px[256];
  char* smc = (char*)sm;
  int tid = threadIdx.x, lane = tid&63, wv = tid>>6;
  int l31 = lane&31, hi = lane>>5;
  int qi = wv>>1, kj = wv&1;
  int L = blockIdx.x;
  int xcd = L&7, iw = L>>3;            // iw 0..63
  int bh = xcd*4 + (iw>>4);            // consecutive iw share bh (L1/L2 reuse)
  int qx = iw&15;
  int qb = qx*128;
  int b = bh>>4, h = bh&15;
  const u16* Kb = kp + (size_t)bh*S_*HD_;
  const u16* Qb = qp + (size_t)bh*S_*HD_;
  int q0 = qb + qi*64;

  bf16x8 qf[2][4];
  #pragma unroll
  for (int f=0;f<2;++f)
    #pragma unroll
    for (int kk=0;kk<4;++kk)
      qf[f][kk] = *reinterpret_cast<const bf16x8*>(Qb + (size_t)(q0 + f*32 + l31)*HD_ + kk*16 + hi*8);

  f32x16 z16 = {};
  f32x2 p4a[2] = {{0.f,0.f},{0.f,0.f}};
  f32x2 p4b[2] = {{0.f,0.f},{0.f,0.f}};

  const char* kSrcC[4];
  #pragma unroll
  for (int c=0;c<4;++c){
    int rk = wv*32 + c*8 + (lane>>3);
    int ck = ((lane&7)*16) ^ ((rk&7)<<4);
    kSrcC[c] = (const char*)Kb + (size_t)rk*128 + ck;
  }

  auto STAGE_K = [&](int bsel, int kt){
    char* db = smc + bsel*16384 + wv*4096;
    #pragma unroll
    for (int c=0;c<4;++c) gl_lds16(kSrcC[c] + (size_t)kt*16384, db + c*1024);
  };

  auto P4ACC = [&](const f32x16& e, f32x2& pa){
    #pragma unroll
    for (int j=0;j<8;++j){
      f32x2 pr = {e[2*j], e[2*j+1]};
      f32x2 e2;
      asm("v_pk_mul_f32 %0, %1, %1" : "=v"(e2) : "v"(pr));
      asm("v_pk_fma_f32 %0, %1, %1, %0" : "+v"(pa) : "v"(e2));
    }
  };

  auto QK = [&](const unsigned char* K_, int s2, f32x16& E0, f32x16& E1){
    bf16x8 ka[4];
    #pragma unroll
    for (int kk=0;kk<4;++kk) ka[kk] = ldfrag(K_, kj*64 + s2*32 + l31, kk*32 + hi*16);
    E0 = z16; E1 = z16;
    __builtin_amdgcn_s_setprio(1);
    #pragma unroll
    for (int kk=0;kk<4;++kk){
      E0 = __builtin_amdgcn_mfma_f32_32x32x16_bf16(ka[kk], qf[0][kk], E0, 0,0,0);
      E1 = __builtin_amdgcn_mfma_f32_32x32x16_bf16(ka[kk], qf[1][kk], E1, 0,0,0);
    }
    __builtin_amdgcn_s_setprio(0);
  };

  const int NT = S_/128;   // 16
  STAGE_K(0, 0); STAGE_K(1, 1);

  f32x16 eA0, eA1, eB0, eB1;

  #pragma unroll 1
  for (int t=0; t<NT; ++t){
    if (t < NT-1) { asm volatile("s_waitcnt vmcnt(4)" ::: "memory"); }
    else          { asm volatile("s_waitcnt vmcnt(0)" ::: "memory"); }
    __builtin_amdgcn_s_barrier();
    asm volatile("" ::: "memory");
    if (t+2 < NT) STAGE_K((t+2)%3, t+2);

    const unsigned char* K_ = sm + (t%3)*16384;
    QK(K_, 0, eA0, eA1);
    QK(K_, 1, eB0, eB1);
    P4ACC(eA0, p4a[0]);
    P4ACC(eA1, p4a[1]);
    P4ACC(eB0, p4b[0]);
    P4ACC(eB1, p4b[1]);
  }

  float p4f[2];
  #pragma unroll
  for (int f=0;f<2;++f){
    p4f[f] = p4a[f].x + p4a[f].y + p4b[f].x + p4b[f].y;
    p4f[f] += __shfl_xor(p4f[f], 32);
  }
  __syncthreads();
  if (hi==0){
    px[((qi*2+0)*2+kj)*32 + l31] = p4f[0];
    px[((qi*2+1)*2+kj)*32 + l31] = p4f[1];
  }
  __syncthreads();
  #pragma unroll
  for (int f=0;f<2;++f) p4f[f] += px[((qi*2+f)*2+(1-kj))*32 + l31];
  float sc0 = GAMMA * rsqrtf(sqrtf(p4f[0]));
  float sc1 = GAMMA * rsqrtf(sqrtf(p4f[1]));

  const u16* mtb = MT + (size_t)bh*4096;
  bf16x8 mtf[4];
  #pragma unroll
  for (int kk=0;kk<4;++kk)
    mtf[kk] = *reinterpret_cast<const bf16x8*>(mtb + (kj*32 + l31)*64 + kk*16 + hi*8);
  f32x16 oA0 = z16, oA1 = z16;
  #pragma unroll
  for (int kk=0;kk<4;++kk){
    oA0 = __builtin_amdgcn_mfma_f32_32x32x16_bf16(mtf[kk], qf[0][kk], oA0, 0,0,0);
    oA1 = __builtin_amdgcn_mfma_f32_32x32x16_bf16(mtf[kk], qf[1][kk], oA1, 0,0,0);
  }

  __syncthreads();
  #pragma unroll
  for (int r=0;r<16;r+=2){
    int e = kj*32 + (r&3) + 8*(r>>2) + 4*hi;
    int ql0 = qi*64 + l31;
    *(u32*)(smc + ql0*128 + SWZ(ql0, e*2)) = cvt_pk_bf16(oA0[r]*sc0, oA0[r+1]*sc0);
    int ql1 = qi*64 + 32 + l31;
    *(u32*)(smc + ql1*128 + SWZ(ql1, e*2)) = cvt_pk_bf16(oA1[r]*sc1, oA1[r+1]*sc1);
  }
  __syncthreads();
  {
    int row = tid>>1, eh = tid&1;
    u16* dst = ao + ((size_t)b*S_ + qb + row)*E_ + h*HD_ + eh*32;
    #pragma unroll
    for (int c=0;c<4;++c)
      *(uint4*)(dst + c*8) = *(const uint4*)(smc + row*128 + SWZ(row, eh*64 + c*16));
  }
}

// ---------------- K3/K5: 128x128-tile bf16 GEMM, 64x64 per wave ----------------
template<int MODE>
__global__ __launch_bounds__(256, 2) void k_gemm(
    const u16* __restrict__ A, const u16* __restrict__ Bw,
    const float* __restrict__ bias, const float* __restrict__ auxf,
    const u16* __restrict__ aux16, float* __restrict__ out32, u16* __restrict__ out16)
{
  __shared__ alignas(128) unsigned char sm[65536];
  char* smc = (char*)sm;
  int tid = threadIdx.x, lane = tid&63, wv = tid>>6;
  int l31 = lane&31, hi = lane>>5;
  int wr = wv>>1, wc = wv&1;
  int LL = (blockIdx.x & 7)*32 + (blockIdx.x >> 3);
  int mt = LL >> 3, nt = LL & 7;
  int m0 = mt*128, n0 = nt*128;

  const char* aS[4]; const char* bS[4];
  #pragma unroll
  for (int c=0;c<4;++c){
    int off = wv*4096 + c*1024 + lane*16;
    int r = off>>7, cl = off&127;
    int cs = cl ^ ((r&7)<<4);
    aS[c] = (const char*)A  + ((size_t)(m0+r)*E_)*2 + cs;
    bS[c] = (const char*)Bw + ((size_t)(n0+r)*E_)*2 + cs;
  }

  auto STAGE = [&](int bsel, int t){
    char* db = smc + bsel*32768 + wv*4096;
    size_t kb2 = (size_t)t*128;
    #pragma unroll
    for (int c=0;c<4;++c) gl_lds16(aS[c] + kb2, db + c*1024);
    #pragma unroll
    for (int c=0;c<4;++c) gl_lds16(bS[c] + kb2, db + 16384 + c*1024);
  };

  f32x16 acc[2][2] = {{{}, {}}, {{}, {}}};

  const int NK = E_/64;
  STAGE(0, 0); STAGE(1, 1);

  #pragma unroll 1
  for (int t=0; t<NK; ++t){
    if (t < NK-1) { asm volatile("s_waitcnt vmcnt(8)" ::: "memory"); }
    else          { asm volatile("s_waitcnt vmcnt(0)" ::: "memory"); }
    __builtin_amdgcn_s_barrier();
    asm volatile("" ::: "memory");

    const unsigned char* Ap_ = sm + (t&1)*32768;
    const unsigned char* Bp_ = Ap_ + 16384;
    #pragma unroll
    for (int kk=0;kk<4;++kk){
      int kbyte = kk*32 + hi*16;
      bf16x8 a0 = ldfrag(Ap_, wr*64 + l31,      kbyte);
      bf16x8 a1 = ldfrag(Ap_, wr*64 + 32 + l31, kbyte);
      bf16x8 b0 = ldfrag(Bp_, wc*64 + l31,      kbyte);
      bf16x8 b1 = ldfrag(Bp_, wc*64 + 32 + l31, kbyte);
      __builtin_amdgcn_s_setprio(1);
      acc[0][0] = __builtin_amdgcn_mfma_f32_32x32x16_bf16(a0, b0, acc[0][0], 0,0,0);
      acc[0][1] = __builtin_amdgcn_mfma_f32_32x32x16_bf16(a0, b1, acc[0][1], 0,0,0);
      acc[1][0] = __builtin_amdgcn_mfma_f32_32x32x16_bf16(a1, b0, acc[1][0], 0,0,0);
      acc[1][1] = __builtin_amdgcn_mfma_f32_32x32x16_bf16(a1, b1, acc[1][1], 0,0,0);
      __builtin_amdgcn_s_setprio(0);
    }

    asm volatile("" ::: "memory");
    __builtin_amdgcn_s_barrier();
    asm volatile("" ::: "memory");
    if (t+2 < NK) STAGE(t&1, t+2);
  }

  #pragma unroll
  for (int cg=0;cg<2;++cg){
    int col = n0 + wc*64 + cg*32 + l31;
    float bi = bias[col];
    #pragma unroll
    for (int rg=0;rg<2;++rg)
      #pragma unroll
      for (int r=0;r<16;++r){
        int mrow = m0 + wr*64 + rg*32 + (r&3) + 8*(r>>2) + 4*hi;
        size_t idx = (size_t)mrow*E_ + col;
        float v = acc[rg][cg][r] + bi;
        if (MODE == 0){
          out16[idx] = f2bf(v + auxf[idx]);
        } else {
          float gg = 1.f/(1.f + __expf(-v));
          out32[idx] = bf2f(aux16[idx]) * gg;
        }
      }
  }
}

// ---------------- K4: LayerNorm over embed dim; bf16 in -> bf16 out ----------------
__global__ __launch_bounds__(256) void k_ln(
    const u16* __restrict__ xin, const float* __restrict__ lnw, const float* __restrict__ lnb,
    u16* __restrict__ xout)
{
  __shared__ float red[8];
  __shared__ float stats[2];
  int row = blockIdx.x, tid = threadIdx.x;
  ushort4 xr = reinterpret_cast<const ushort4*>(xin + (size_t)row*E_)[tid];
  float x0 = bf2f(xr.x), x1 = bf2f(xr.y), x2 = bf2f(xr.z), x3 = bf2f(xr.w);
  float s  = x0 + x1 + x2 + x3;
  float s2 = x0*x0 + x1*x1 + x2*x2 + x3*x3;
  #pragma unroll
  for (int m=1;m<64;m<<=1){ s += __shfl_xor(s,m); s2 += __shfl_xor(s2,m); }
  if ((tid&63)==0){ red[tid>>6] = s; red[4+(tid>>6)] = s2; }
  __syncthreads();
  if (tid==0){
    float ts  = red[0]+red[1]+red[2]+red[3];
    float ts2 = red[4]+red[5]+red[6]+red[7];
    float mu  = ts * (1.f/E_);
    float var = ts2 * (1.f/E_) - mu*mu;
    stats[0] = mu; stats[1] = rsqrtf(var + 1e-5f);
  }
  __syncthreads();
  float mu = stats[0], rstd = stats[1];
  float4 w  = reinterpret_cast<const float4*>(lnw)[tid];
  float4 bb = reinterpret_cast<const float4*>(lnb)[tid];
  ushort4 p;
  p.x = f2bf((x0-mu)*rstd*w.x + bb.x);
  p.y = f2bf((x1-mu)*rstd*w.y + bb.y);
  p.z = f2bf((x2-mu)*rstd*w.z + bb.z);
  p.w = f2bf((x3-mu)*rstd*w.w + bb.w);
  reinterpret_cast<ushort4*>(xout + (size_t)row*E_)[tid] = p;
}

// ---------------- host launch ----------------
extern "C" void kernel_launch(void* const* d_in, const int* in_sizes, int n_in,
                              void* d_out, int out_size, void* d_ws, size_t ws_size,
                              hipStream_t stream)
{
  const float* value = (const float*)d_in[0];
  const float* key   = (const float*)d_in[1];
  const float* query = (const float*)d_in[2];
  const float* Wq    = (const float*)d_in[3];
  const float* Wk    = (const float*)d_in[4];
  const float* Wv    = (const float*)d_in[5];
  const float* Wo    = (const float*)d_in[6];
  const float* bo    = (const float*)d_in[7];
  const float* lnw   = (const float*)d_in[8];
  const float* lnb   = (const float*)d_in[9];
  const float* Wsq   = (const float*)d_in[10];
  const float* bsq   = (const float*)d_in[11];
  float* out = (float*)d_out;

  char* ws = (char*)d_ws;
  const size_t MB = 1ull<<20;
  u16*   qp     = (u16*)(ws + 0*MB);    // K1->K2b
  u16*   kp     = (u16*)(ws + 8*MB);    // K1->K2b
  u16*   vnT    = (u16*)(ws + 16*MB);   // K1->K2a
  u16*   kpT    = (u16*)(ws + 24*MB);   // K1->K2a
  u16*   ao     = (u16*)(ws + 32*MB);   // K2b->K3 (8MB)
  u16*   mtw    = (u16*)(ws + 44*MB);   // K2a'->K2b (256KB)
  u16*   xres16 = (u16*)(ws + 8*MB);    // K3->K4 (over kp, dead after attn)
  u16*   x16    = (u16*)(ws + 16*MB);   // K4->K5 (over vnT, dead after k_kv)
  float* part   = (float*)(ws + 64*MB); // K2a->K2a' (16MB fp32 partials)
  u16*   wo16   = (u16*)(ws + 48*MB);
  u16*   wsq16  = (u16*)(ws + 50*MB);

  k_proj<<<dim3(N_/64, H_+2), 256, 0, stream>>>(query, key, value, Wq, Wk, Wv,
                                                qp, kp, kpT, vnT, Wo, Wsq, wo16, wsq16);
  k_kv  <<<256, 256, 0, stream>>>(kpT, vnT, part);
  k_kvr <<<BH_, 256, 0, stream>>>(part, mtw);
  k_attn<<<512, 256, 0, stream>>>(qp, kp, mtw, ao);
  k_gemm<0><<<256, 256, 0, stream>>>(ao, wo16, bo, query, (const u16*)nullptr, (float*)nullptr, xres16);
  k_ln  <<<N_, 256, 0, stream>>>(xres16, lnw, lnb, x16);
  k_gemm<1><<<256, 256, 0, stream>>>(x16, wsq16, bsq, (const float*)nullptr, x16, out, (u16*)nullptr);
}

// Round 17
// 110.579 us; speedup vs baseline: 1.0113x; 1.0046x over previous
//
#include <hip/hip_runtime.h>
#include <stdint.h>

#define B_ 2
#define S_ 2048
#define E_ 1024
#define H_ 16
#define HD_ 64
#define N_ (B_*S_)
#define BH_ (B_*H_)
#define GAMMA 0.01f

typedef __attribute__((ext_vector_type(8))) short bf16x8;
typedef __attribute__((ext_vector_type(4))) float f32x4;
typedef __attribute__((ext_vector_type(2))) float f32x2;
typedef __attribute__((ext_vector_type(16))) float f32x16;
typedef unsigned short u16;
typedef unsigned int u32;

// byte-level XOR swizzle within a 128B row
#define SWZ(row, kb) ((kb) ^ (((row)&7)<<4))

__device__ __forceinline__ u16 f2bf(float f){
  union { float f; u32 u; } v; v.f = f;
  return (u16)((v.u + 0x7FFFu + ((v.u>>16)&1u)) >> 16);
}

__device__ __forceinline__ float bf2f(u16 u){
  union { u32 u; float f; } v; v.u = ((u32)u)<<16; return v.f;
}

__device__ __forceinline__ u32 cvt_pk_bf16(float lo, float hi){
  u32 r; asm("v_cvt_pk_bf16_f32 %0, %1, %2" : "=v"(r) : "v"(lo), "v"(hi)); return r;
}

__device__ __forceinline__ uint4 pack8(float4 a, float4 b){
  uint4 r;
  r.x = cvt_pk_bf16(a.x, a.y);
  r.y = cvt_pk_bf16(a.z, a.w);
  r.z = cvt_pk_bf16(b.x, b.y);
  r.w = cvt_pk_bf16(b.z, b.w);
  return r;
}

__device__ __forceinline__ bf16x8 ldfrag(const unsigned char* base, int row, int kbyte){
  return *reinterpret_cast<const bf16x8*>(base + row*128 + SWZ(row, kbyte));
}

// async global->LDS, 16B/lane; LDS dest linear, source pre-swizzled
__device__ __forceinline__ void gl_lds16(const void* g, void* l){
  __builtin_amdgcn_global_load_lds(
      (const __attribute__((address_space(1))) unsigned int*)g,
      (__attribute__((address_space(3))) unsigned int*)l, 16, 0, 0);
}

// ---------------- K1: per-head QKV projection + xnorm(v); emits qp, kp, kpT, vnT ----------------
__device__ __forceinline__ void proj_mfma(const unsigned char* X, const unsigned char* W,
                                          int wid, int l15, int g4, f32x4 acc[4])
{
  f32x4 z = {0.f,0.f,0.f,0.f};
  acc[0]=z; acc[1]=z; acc[2]=z; acc[3]=z;
  #pragma unroll
  for (int kk=0;kk<2;++kk){
    int kbyte = kk*64 + g4*16;
    bf16x8 a = ldfrag(X, wid*16 + l15, kbyte);
    #pragma unroll
    for (int t=0;t<4;++t){
      bf16x8 w = ldfrag(W, t*16 + l15, kbyte);
      acc[t] = __builtin_amdgcn_mfma_f32_16x16x32_bf16(a, w, acc[t], 0, 0, 0);
    }
  }
}

__global__ __launch_bounds__(256) void k_proj(
    const float* __restrict__ qin, const float* __restrict__ kin, const float* __restrict__ vin,
    const float* __restrict__ Wq, const float* __restrict__ Wk, const float* __restrict__ Wv,
    u16* __restrict__ qp, u16* __restrict__ kp, u16* __restrict__ kpT, u16* __restrict__ vnT,
    const float* __restrict__ Wo, const float* __restrict__ Wsq,
    u16* __restrict__ wo16, u16* __restrict__ wsq16)
{
  __shared__ alignas(16) unsigned char sm[49152];
  if (blockIdx.y >= H_){
    int cblk = (blockIdx.y - H_)*64 + blockIdx.x;
    int n4 = (E_*E_)/4;
    for (int i = cblk*256 + threadIdx.x; i < 2*n4; i += 128*256){
      const float4* src; ushort4* dst; int j;
      if (i < n4){ src=(const float4*)Wo;  dst=(ushort4*)wo16;  j=i; }
      else       { src=(const float4*)Wsq; dst=(ushort4*)wsq16; j=i-n4; }
      float4 v = src[j];
      ushort4 p; p.x=f2bf(v.x); p.y=f2bf(v.y); p.z=f2bf(v.z); p.w=f2bf(v.w);
      dst[j] = p;
    }
    return;
  }
  const int XQ=0, XK=8192, XV=16384, WQS=24576, WKS=32768, WVS=40960;
  int tid = threadIdx.x, lane = tid&63, wid = tid>>6;
  int l15 = lane&15, g4 = lane>>4;
  int tb = blockIdx.x*64;
  int h  = blockIdx.y;
  int b  = tb >> 11;
  int sbase = tb & 2047;
  int bh = b*H_ + h;

  {
    int rl = tid>>2;
    int d0 = (tid&3)*16;
    const float* xs[3] = { qin, kin, vin };
    const float* wsrc[3] = { Wq, Wk, Wv };
    const int xoff[3] = {XQ,XK,XV}, woff[3] = {WQS,WKS,WVS};
    #pragma unroll
    for (int m3=0;m3<3;++m3){
      const float4* gx = reinterpret_cast<const float4*>(xs[m3] + (size_t)(tb+rl)*E_ + h*HD_ + d0);
      float4 a=gx[0], bb=gx[1], c=gx[2], d=gx[3];
      *(uint4*)(sm + xoff[m3] + rl*128 + SWZ(rl, d0*2))    = pack8(a,bb);
      *(uint4*)(sm + xoff[m3] + rl*128 + SWZ(rl, d0*2+16)) = pack8(c,d);
      const float4* gw = reinterpret_cast<const float4*>(wsrc[m3] + rl*64 + d0);
      float4 e=gw[0], f=gw[1], g2=gw[2], h2=gw[3];
      *(uint4*)(sm + woff[m3] + rl*128 + SWZ(rl, d0*2))    = pack8(e,f);
      *(uint4*)(sm + woff[m3] + rl*128 + SWZ(rl, d0*2+16)) = pack8(g2,h2);
    }
  }
  __syncthreads();

  f32x4 qacc[4], kacc[4], vacc[4];
  proj_mfma(sm+XQ, sm+WQS, wid, l15, g4, qacc);
  proj_mfma(sm+XK, sm+WKS, wid, l15, g4, kacc);
  proj_mfma(sm+XV, sm+WVS, wid, l15, g4, vacc);

  {
    float p4r[4] = {0.f,0.f,0.f,0.f};
    #pragma unroll
    for (int t=0;t<4;++t)
      #pragma unroll
      for (int r=0;r<4;++r){ float e = vacc[t][r]; float e2 = e*e; p4r[r] += e2*e2; }
    #pragma unroll
    for (int r=0;r<4;++r){
      float p = p4r[r];
      p += __shfl_xor(p,1); p += __shfl_xor(p,2); p += __shfl_xor(p,4); p += __shfl_xor(p,8);
      p4r[r] = GAMMA / sqrtf(sqrtf(p));
    }
    #pragma unroll
    for (int t=0;t<4;++t)
      #pragma unroll
      for (int r=0;r<4;++r) vacc[t][r] *= p4r[r];
  }

  __syncthreads();   // X/W dead; reuse XQ/XK/XV/WQS as output staging

  #pragma unroll
  for (int t=0;t<4;++t){
    int dd = t*16 + l15;
    #pragma unroll
    for (int r=0;r<4;++r){
      int tokl = wid*16 + g4*4 + r;
      *(u16*)(sm + XQ + tokl*128 + SWZ(tokl, dd*2)) = f2bf(qacc[t][r]);
      *(u16*)(sm + XK + tokl*128 + SWZ(tokl, dd*2)) = f2bf(kacc[t][r]);
    }
    #pragma unroll
    for (int r=0;r<4;r+=2){
      int tokl = wid*16 + g4*4 + r;
      *(u32*)(sm + XV  + dd*128 + SWZ(dd, tokl*2)) = cvt_pk_bf16(vacc[t][r], vacc[t][r+1]);
      *(u32*)(sm + WQS + dd*128 + SWZ(dd, tokl*2)) = cvt_pk_bf16(kacc[t][r], kacc[t][r+1]);
    }
  }
  __syncthreads();

  {
    int rl = tid>>2; int c2 = tid&3;
    uint4 q0 = *(const uint4*)(sm + XQ + rl*128 + SWZ(rl, c2*32));
    uint4 q1 = *(const uint4*)(sm + XQ + rl*128 + SWZ(rl, c2*32+16));
    size_t qg = ((size_t)bh*S_ + sbase + rl)*HD_ + c2*16;
    *(uint4*)(qp + qg)     = q0;
    *(uint4*)(qp + qg + 8) = q1;
    uint4 k0 = *(const uint4*)(sm + XK + rl*128 + SWZ(rl, c2*32));
    uint4 k1 = *(const uint4*)(sm + XK + rl*128 + SWZ(rl, c2*32+16));
    *(uint4*)(kp + qg)     = k0;
    *(uint4*)(kp + qg + 8) = k1;
    size_t vg = ((size_t)bh*HD_ + rl)*S_ + sbase + c2*16;
    uint4 v0 = *(const uint4*)(sm + XV + rl*128 + SWZ(rl, c2*32));
    uint4 v1 = *(const uint4*)(sm + XV + rl*128 + SWZ(rl, c2*32+16));
    *(uint4*)(vnT + vg)     = v0;
    *(uint4*)(vnT + vg + 8) = v1;
    uint4 t0 = *(const uint4*)(sm + WQS + rl*128 + SWZ(rl, c2*32));
    uint4 t1 = *(const uint4*)(sm + WQS + rl*128 + SWZ(rl, c2*32+16));
    *(uint4*)(kpT + vg)     = t0;
    *(uint4*)(kpT + vg + 8) = t1;
  }
}

// ---------------- K2a: partial MT = sum_{s in chunk} Vn[s][e]*K[s][d] ----------------
__global__ __launch_bounds__(256) void k_kv(
    const u16* __restrict__ kpT, const u16* __restrict__ vnT, float* __restrict__ part)
{
  __shared__ alignas(128) unsigned char sm[65536];   // K 32KB + V 32KB
  char* smc = (char*)sm;
  int tid = threadIdx.x, lane = tid&63, wv = tid>>6;
  int l31 = lane&31, hi = lane>>5;
  int bh = blockIdx.x >> 3, ch = blockIdx.x & 7;
  const char* kt = (const char*)(kpT + (size_t)bh*HD_*S_ + ch*256);
  const char* vt = (const char*)(vnT + (size_t)bh*HD_*S_ + ch*256);

  #pragma unroll
  for (int c=0;c<8;++c){
    int off = wv*8192 + c*1024 + lane*16;
    int row = off>>9, sl = (off&511)>>4;
    int ssl = sl ^ (row&31);
    gl_lds16(kt + (size_t)row*S_*2 + ssl*16, smc + off);
    gl_lds16(vt + (size_t)row*S_*2 + ssl*16, smc + 32768 + off);
  }
  asm volatile("s_waitcnt vmcnt(0)" ::: "memory");
  __builtin_amdgcn_s_barrier();
  asm volatile("" ::: "memory");

  auto LD = [&](int mo, int row, int byte) -> bf16x8 {
    return *reinterpret_cast<const bf16x8*>(smc + mo + row*512 + (byte ^ ((row&31)<<4)));
  };

  f32x16 acc[2][2] = {{{}, {}}, {{}, {}}};
  #pragma unroll
  for (int it=0; it<4; ++it){
    int kb = wv*128 + it*32 + hi*16;
    bf16x8 ka0 = LD(0,     l31,    kb);
    bf16x8 ka1 = LD(0,     32+l31, kb);
    bf16x8 vb0 = LD(32768, l31,    kb);
    bf16x8 vb1 = LD(32768, 32+l31, kb);
    acc[0][0] = __builtin_amdgcn_mfma_f32_32x32x16_bf16(ka0, vb0, acc[0][0], 0,0,0);
    acc[0][1] = __builtin_amdgcn_mfma_f32_32x32x16_bf16(ka1, vb0, acc[0][1], 0,0,0);
    acc[1][0] = __builtin_amdgcn_mfma_f32_32x32x16_bf16(ka0, vb1, acc[1][0], 0,0,0);
    acc[1][1] = __builtin_amdgcn_mfma_f32_32x32x16_bf16(ka1, vb1, acc[1][1], 0,0,0);
  }

  float* dstw = part + ((size_t)blockIdx.x*4 + wv)*4096;
  #pragma unroll
  for (int eh=0;eh<2;++eh)
    #pragma unroll
    for (int dh=0;dh<2;++dh){
      float* d2 = dstw + ((eh*2+dh)*64 + lane)*16;
      #pragma unroll
      for (int r4=0;r4<4;++r4)
        *(float4*)(d2 + r4*4) = make_float4(acc[eh][dh][r4*4],acc[eh][dh][r4*4+1],
                                            acc[eh][dh][r4*4+2],acc[eh][dh][r4*4+3]);
    }
}

// ---------------- K2a': reduce 32 partials per bh, emit row-major bf16 MT ----------------
__global__ __launch_bounds__(256) void k_kvr(
    const float* __restrict__ part, u16* __restrict__ MT)
{
  int tid = threadIdx.x, lane = tid&63, quad = tid>>6;
  int l31 = lane&31, hi = lane>>5;
  int bh = blockIdx.x;
  float s[16] = {0,0,0,0,0,0,0,0,0,0,0,0,0,0,0,0};
  #pragma unroll 4
  for (int p=0;p<32;++p){
    const float* src = part + ((size_t)(bh*8 + (p>>2))*4 + (p&3))*4096 + (quad*64 + lane)*16;
    #pragma unroll
    for (int r4=0;r4<4;++r4){
      float4 t = *(const float4*)(src + r4*4);
      s[r4*4]+=t.x; s[r4*4+1]+=t.y; s[r4*4+2]+=t.z; s[r4*4+3]+=t.w;
    }
  }
  int eh = quad>>1, dh = quad&1;
  int e = eh*32 + l31;
  u16* dst = MT + (size_t)bh*4096 + e*64;
  #pragma unroll
  for (int r=0;r<16;r+=2){
    int d = dh*32 + (r&3) + 8*(r>>2) + 4*hi;
    *(u32*)(dst + d) = cvt_pk_bf16(s[r], s[r+1]);
  }
}

// ---------------- K2b: QK^T -> p4; out = Q @ MT. 64q/block, 4 kj-quarter waves ----------------
// Grid 1024 = 4 blocks/CU (LDS 33KB, VGPR<=128 via launch_bounds(256,4)). Per
// 128-key tile per wave: 4 ds_read -> 8 MFMA + 32 pk-VALU. 2x16KB K dbuf, 2
// barriers/tile, vmcnt(4). Independent blocks overlap each other's stalls.
__global__ __launch_bounds__(256, 4) void k_attn(
    const u16* __restrict__ qp, const u16* __restrict__ kp,
    const u16* __restrict__ MT, u16* __restrict__ ao)
{
  __shared__ alignas(128) unsigned char sm[32768];   // 2 x 16KB K; reused by epilogue
  __shared__ float px[4][2][32];
  char* smc = (char*)sm;
  int tid = threadIdx.x, lane = tid&63, kj = tid>>6;
  int l31 = lane&31, hi = lane>>5;
  int L = blockIdx.x;
  int xcd = L&7, iw = L>>3;            // iw 0..127
  int bh = xcd*4 + (iw>>5);            // consecutive iw share bh (L1/L2 reuse)
  int qx = iw&31;                      // 0..31
  int qb = qx*64;
  int b = bh>>4, h = bh&15;
  const u16* Kb = kp + (size_t)bh*S_*HD_;
  const u16* Qb = qp + (size_t)bh*S_*HD_;

  // Q fragments: 2 q-frags of 32 rows (block owns 64 q-rows)
  bf16x8 qf[2][4];
  #pragma unroll
  for (int f=0;f<2;++f)
    #pragma unroll
    for (int kk=0;kk<4;++kk)
      qf[f][kk] = *reinterpret_cast<const bf16x8*>(Qb + (size_t)(qb + f*32 + l31)*HD_ + kk*16 + hi*8);

  f32x16 z16 = {};
  f32x2 p4a[2] = {{0.f,0.f},{0.f,0.f}};

  // staging: wave kj covers K rows kj*32..+31 (4 gl_lds of 1KB)
  const char* kSrcC[4];
  #pragma unroll
  for (int c=0;c<4;++c){
    int rk = kj*32 + c*8 + (lane>>3);
    int ck = ((lane&7)*16) ^ ((rk&7)<<4);
    kSrcC[c] = (const char*)Kb + (size_t)rk*128 + ck;
  }
  auto STAGE_K = [&](int bsel, int kt){
    char* db = smc + bsel*16384 + kj*4096;
    #pragma unroll
    for (int c=0;c<4;++c) gl_lds16(kSrcC[c] + (size_t)kt*16384, db + c*1024);
  };

  auto P4ACC = [&](const f32x16& e, f32x2& pa){
    #pragma unroll
    for (int j=0;j<8;++j){
      f32x2 pr = {e[2*j], e[2*j+1]};
      f32x2 e2;
      asm("v_pk_mul_f32 %0, %1, %1" : "=v"(e2) : "v"(pr));
      asm("v_pk_fma_f32 %0, %1, %1, %0" : "+v"(pa) : "v"(e2));
    }
  };

  const int NT = S_/128;   // 16
  STAGE_K(0, 0); STAGE_K(1, 1);

  #pragma unroll 1
  for (int t=0; t<NT; ++t){
    if (t < NT-1) { asm volatile("s_waitcnt vmcnt(4)" ::: "memory"); }
    else          { asm volatile("s_waitcnt vmcnt(0)" ::: "memory"); }
    __builtin_amdgcn_s_barrier();
    asm volatile("" ::: "memory");
    const unsigned char* K_ = sm + (t&1)*16384;

    // QK^T over this wave's 32-key quarter
    bf16x8 ka[4];
    #pragma unroll
    for (int kk=0;kk<4;++kk) ka[kk] = ldfrag(K_, kj*32 + l31, kk*32 + hi*16);
    f32x16 e0 = z16, e1 = z16;
    __builtin_amdgcn_s_setprio(1);
    #pragma unroll
    for (int kk=0;kk<4;++kk){
      e0 = __builtin_amdgcn_mfma_f32_32x32x16_bf16(ka[kk], qf[0][kk], e0, 0,0,0);
      e1 = __builtin_amdgcn_mfma_f32_32x32x16_bf16(ka[kk], qf[1][kk], e1, 0,0,0);
    }
    __builtin_amdgcn_s_setprio(0);
    P4ACC(e0, p4a[0]);
    P4ACC(e1, p4a[1]);

    asm volatile("" ::: "memory");
    __builtin_amdgcn_s_barrier();      // all waves done reading buf[t&1]
    asm volatile("" ::: "memory");
    if (t+2 < NT) STAGE_K(t&1, t+2);
  }

  // ---- p4: lane-fold, cross-half, cross-wave via px ----
  float p4f[2];
  #pragma unroll
  for (int f=0;f<2;++f){
    p4f[f] = p4a[f].x + p4a[f].y;
    p4f[f] += __shfl_xor(p4f[f], 32);
  }
  if (hi==0){ px[kj][0][l31] = p4f[0]; px[kj][1][l31] = p4f[1]; }
  __syncthreads();
  float sc0, sc1;
  {
    float t0 = px[0][0][l31]+px[1][0][l31]+px[2][0][l31]+px[3][0][l31];
    float t1 = px[0][1][l31]+px[1][1][l31]+px[2][1][l31]+px[3][1][l31];
    sc0 = GAMMA * rsqrtf(sqrtf(t0));
    sc1 = GAMMA * rsqrtf(sqrtf(t1));
  }

  // ---- out = Q @ MT: waves 0,1 each compute one e-half (8 MFMAs) ----
  if (kj < 2){
    const u16* mtb = MT + (size_t)bh*4096;
    bf16x8 mtf[4];
    #pragma unroll
    for (int kk=0;kk<4;++kk)
      mtf[kk] = *reinterpret_cast<const bf16x8*>(mtb + (kj*32 + l31)*64 + kk*16 + hi*8);
    f32x16 oA0 = z16, oA1 = z16;
    #pragma unroll
    for (int kk=0;kk<4;++kk){
      oA0 = __builtin_amdgcn_mfma_f32_32x32x16_bf16(mtf[kk], qf[0][kk], oA0, 0,0,0);
      oA1 = __builtin_amdgcn_mfma_f32_32x32x16_bf16(mtf[kk], qf[1][kk], oA1, 0,0,0);
    }
    // scale + LDS transpose write: tile [64 q][64 e] at smc base
    #pragma unroll
    for (int r=0;r<16;r+=2){
      int e = kj*32 + (r&3) + 8*(r>>2) + 4*hi;
      *(u32*)(smc + l31*128      + SWZ(l31,      e*2)) = cvt_pk_bf16(oA0[r]*sc0, oA0[r+1]*sc0);
      *(u32*)(smc + (32+l31)*128 + SWZ(32+l31,   e*2)) = cvt_pk_bf16(oA1[r]*sc1, oA1[r+1]*sc1);
    }
  }
  __syncthreads();
  { // coalesced store: 64 rows x 128B
    int row = tid>>2, c2 = tid&3;
    u16* dst = ao + ((size_t)b*S_ + qb + row)*E_ + h*HD_ + c2*16;
    *(uint4*)dst       = *(const uint4*)(smc + row*128 + SWZ(row, c2*32));
    *(uint4*)(dst + 8) = *(const uint4*)(smc + row*128 + SWZ(row, c2*32+16));
  }
}

// ---------------- K3/K5: 128x128-tile bf16 GEMM, 64x64 per wave ----------------
template<int MODE>
__global__ __launch_bounds__(256, 2) void k_gemm(
    const u16* __restrict__ A, const u16* __restrict__ Bw,
    const float* __restrict__ bias, const float* __restrict__ auxf,
    const u16* __restrict__ aux16, float* __restrict__ out32, u16* __restrict__ out16)
{
  __shared__ alignas(128) unsigned char sm[65536];
  char* smc = (char*)sm;
  int tid = threadIdx.x, lane = tid&63, wv = tid>>6;
  int l31 = lane&31, hi = lane>>5;
  int wr = wv>>1, wc = wv&1;
  int LL = (blockIdx.x & 7)*32 + (blockIdx.x >> 3);
  int mt = LL >> 3, nt = LL & 7;
  int m0 = mt*128, n0 = nt*128;

  const char* aS[4]; const char* bS[4];
  #pragma unroll
  for (int c=0;c<4;++c){
    int off = wv*4096 + c*1024 + lane*16;
    int r = off>>7, cl = off&127;
    int cs = cl ^ ((r&7)<<4);
    aS[c] = (const char*)A  + ((size_t)(m0+r)*E_)*2 + cs;
    bS[c] = (const char*)Bw + ((size_t)(n0+r)*E_)*2 + cs;
  }

  auto STAGE = [&](int bsel, int t){
    char* db = smc + bsel*32768 + wv*4096;
    size_t kb2 = (size_t)t*128;
    #pragma unroll
    for (int c=0;c<4;++c) gl_lds16(aS[c] + kb2, db + c*1024);
    #pragma unroll
    for (int c=0;c<4;++c) gl_lds16(bS[c] + kb2, db + 16384 + c*1024);
  };

  f32x16 acc[2][2] = {{{}, {}}, {{}, {}}};

  const int NK = E_/64;
  STAGE(0, 0); STAGE(1, 1);

  #pragma unroll 1
  for (int t=0; t<NK; ++t){
    if (t < NK-1) { asm volatile("s_waitcnt vmcnt(8)" ::: "memory"); }
    else          { asm volatile("s_waitcnt vmcnt(0)" ::: "memory"); }
    __builtin_amdgcn_s_barrier();
    asm volatile("" ::: "memory");

    const unsigned char* Ap_ = sm + (t&1)*32768;
    const unsigned char* Bp_ = Ap_ + 16384;
    #pragma unroll
    for (int kk=0;kk<4;++kk){
      int kbyte = kk*32 + hi*16;
      bf16x8 a0 = ldfrag(Ap_, wr*64 + l31,      kbyte);
      bf16x8 a1 = ldfrag(Ap_, wr*64 + 32 + l31, kbyte);
      bf16x8 b0 = ldfrag(Bp_, wc*64 + l31,      kbyte);
      bf16x8 b1 = ldfrag(Bp_, wc*64 + 32 + l31, kbyte);
      __builtin_amdgcn_s_setprio(1);
      acc[0][0] = __builtin_amdgcn_mfma_f32_32x32x16_bf16(a0, b0, acc[0][0], 0,0,0);
      acc[0][1] = __builtin_amdgcn_mfma_f32_32x32x16_bf16(a0, b1, acc[0][1], 0,0,0);
      acc[1][0] = __builtin_amdgcn_mfma_f32_32x32x16_bf16(a1, b0, acc[1][0], 0,0,0);
      acc[1][1] = __builtin_amdgcn_mfma_f32_32x32x16_bf16(a1, b1, acc[1][1], 0,0,0);
      __builtin_amdgcn_s_setprio(0);
    }

    asm volatile("" ::: "memory");
    __builtin_amdgcn_s_barrier();
    asm volatile("" ::: "memory");
    if (t+2 < NK) STAGE(t&1, t+2);
  }

  #pragma unroll
  for (int cg=0;cg<2;++cg){
    int col = n0 + wc*64 + cg*32 + l31;
    float bi = bias[col];
    #pragma unroll
    for (int rg=0;rg<2;++rg)
      #pragma unroll
      for (int r=0;r<16;++r){
        int mrow = m0 + wr*64 + rg*32 + (r&3) + 8*(r>>2) + 4*hi;
        size_t idx = (size_t)mrow*E_ + col;
        float v = acc[rg][cg][r] + bi;
        if (MODE == 0){
          out16[idx] = f2bf(v + auxf[idx]);
        } else {
          float gg = 1.f/(1.f + __expf(-v));
          out32[idx] = bf2f(aux16[idx]) * gg;
        }
      }
  }
}

// ---------------- K4: LayerNorm over embed dim; bf16 in -> bf16 out ----------------
__global__ __launch_bounds__(256) void k_ln(
    const u16* __restrict__ xin, const float* __restrict__ lnw, const float* __restrict__ lnb,
    u16* __restrict__ xout)
{
  __shared__ float red[8];
  __shared__ float stats[2];
  int row = blockIdx.x, tid = threadIdx.x;
  ushort4 xr = reinterpret_cast<const ushort4*>(xin + (size_t)row*E_)[tid];
  float x0 = bf2f(xr.x), x1 = bf2f(xr.y), x2 = bf2f(xr.z), x3 = bf2f(xr.w);
  float s  = x0 + x1 + x2 + x3;
  float s2 = x0*x0 + x1*x1 + x2*x2 + x3*x3;
  #pragma unroll
  for (int m=1;m<64;m<<=1){ s += __shfl_xor(s,m); s2 += __shfl_xor(s2,m); }
  if ((tid&63)==0){ red[tid>>6] = s; red[4+(tid>>6)] = s2; }
  __syncthreads();
  if (tid==0){
    float ts  = red[0]+red[1]+red[2]+red[3];
    float ts2 = red[4]+red[5]+red[6]+red[7];
    float mu  = ts * (1.f/E_);
    float var = ts2 * (1.f/E_) - mu*mu;
    stats[0] = mu; stats[1] = rsqrtf(var + 1e-5f);
  }
  __syncthreads();
  float mu = stats[0], rstd = stats[1];
  float4 w  = reinterpret_cast<const float4*>(lnw)[tid];
  float4 bb = reinterpret_cast<const float4*>(lnb)[tid];
  ushort4 p;
  p.x = f2bf((x0-mu)*rstd*w.x + bb.x);
  p.y = f2bf((x1-mu)*rstd*w.y + bb.y);
  p.z = f2bf((x2-mu)*rstd*w.z + bb.z);
  p.w = f2bf((x3-mu)*rstd*w.w + bb.w);
  reinterpret_cast<ushort4*>(xout + (size_t)row*E_)[tid] = p;
}

// ---------------- host launch ----------------
extern "C" void kernel_launch(void* const* d_in, const int* in_sizes, int n_in,
                              void* d_out, int out_size, void* d_ws, size_t ws_size,
                              hipStream_t stream)
{
  const float* value = (const float*)d_in[0];
  const float* key   = (const float*)d_in[1];
  const float* query = (const float*)d_in[2];
  const float* Wq    = (const float*)d_in[3];
  const float* Wk    = (const float*)d_in[4];
  const float* Wv    = (const float*)d_in[5];
  const float* Wo    = (const float*)d_in[6];
  const float* bo    = (const float*)d_in[7];
  const float* lnw   = (const float*)d_in[8];
  const float* lnb   = (const float*)d_in[9];
  const float* Wsq   = (const float*)d_in[10];
  const float* bsq   = (const float*)d_in[11];
  float* out = (float*)d_out;

  char* ws = (char*)d_ws;
  const size_t MB = 1ull<<20;
  u16*   qp     = (u16*)(ws + 0*MB);    // K1->K2b
  u16*   kp     = (u16*)(ws + 8*MB);    // K1->K2b
  u16*   vnT    = (u16*)(ws + 16*MB);   // K1->K2a
  u16*   kpT    = (u16*)(ws + 24*MB);   // K1->K2a
  u16*   ao     = (u16*)(ws + 32*MB);   // K2b->K3 (8MB)
  u16*   mtw    = (u16*)(ws + 44*MB);   // K2a'->K2b (256KB)
  u16*   xres16 = (u16*)(ws + 8*MB);    // K3->K4 (over kp, dead after attn)
  u16*   x16    = (u16*)(ws + 16*MB);   // K4->K5 (over vnT, dead after k_kv)
  float* part   = (float*)(ws + 64*MB); // K2a->K2a' (16MB fp32 partials)
  u16*   wo16   = (u16*)(ws + 48*MB);
  u16*   wsq16  = (u16*)(ws + 50*MB);

  k_proj<<<dim3(N_/64, H_+2), 256, 0, stream>>>(query, key, value, Wq, Wk, Wv,
                                                qp, kp, kpT, vnT, Wo, Wsq, wo16, wsq16);
  k_kv  <<<256, 256, 0, stream>>>(kpT, vnT, part);
  k_kvr <<<BH_, 256, 0, stream>>>(part, mtw);
  k_attn<<<1024, 256, 0, stream>>>(qp, kp, mtw, ao);
  k_gemm<0><<<256, 256, 0, stream>>>(ao, wo16, bo, query, (const u16*)nullptr, (float*)nullptr, xres16);
  k_ln  <<<N_, 256, 0, stream>>>(xres16, lnw, lnb, x16);
  k_gemm<1><<<256, 256, 0, stream>>>(x16, wsq16, bsq, (const float*)nullptr, x16, out, (u16*)nullptr);
}

// Round 18
// 105.339 us; speedup vs baseline: 1.0615x; 1.0497x over previous
//
#include <hip/hip_runtime.h>
#include <stdint.h>

#define B_ 2
#define S_ 2048
#define E_ 1024
#define H_ 16
#define HD_ 64
#define N_ (B_*S_)
#define BH_ (B_*H_)
#define GAMMA 0.01f

typedef __attribute__((ext_vector_type(8))) short bf16x8;
typedef __attribute__((ext_vector_type(4))) float f32x4;
typedef __attribute__((ext_vector_type(2))) float f32x2;
typedef __attribute__((ext_vector_type(16))) float f32x16;
typedef unsigned short u16;
typedef unsigned int u32;

// byte-level XOR swizzle within a 128B row
#define SWZ(row, kb) ((kb) ^ (((row)&7)<<4))

__device__ __forceinline__ u16 f2bf(float f){
  union { float f; u32 u; } v; v.f = f;
  return (u16)((v.u + 0x7FFFu + ((v.u>>16)&1u)) >> 16);
}

__device__ __forceinline__ float bf2f(u16 u){
  union { u32 u; float f; } v; v.u = ((u32)u)<<16; return v.f;
}

__device__ __forceinline__ u32 cvt_pk_bf16(float lo, float hi){
  u32 r; asm("v_cvt_pk_bf16_f32 %0, %1, %2" : "=v"(r) : "v"(lo), "v"(hi)); return r;
}

// packed fp32x8 -> bf16x8 conversion (4 HW instructions)
__device__ __forceinline__ uint4 pack8(float4 a, float4 b){
  uint4 r;
  r.x = cvt_pk_bf16(a.x, a.y);
  r.y = cvt_pk_bf16(a.z, a.w);
  r.z = cvt_pk_bf16(b.x, b.y);
  r.w = cvt_pk_bf16(b.z, b.w);
  return r;
}

__device__ __forceinline__ bf16x8 ldfrag(const unsigned char* base, int row, int kbyte){
  return *reinterpret_cast<const bf16x8*>(base + row*128 + SWZ(row, kbyte));
}
// V tile has 256B rows; 16-slot swizzle
__device__ __forceinline__ bf16x8 ldfragV(const unsigned char* base, int row, int col){
  return *reinterpret_cast<const bf16x8*>(base + row*256 + (col ^ ((row&15)<<4)));
}

// async global->LDS, 16B/lane; LDS dest = wave-uniform base + lane*16 (linear),
// swizzling achieved by permuting the per-lane SOURCE address
__device__ __forceinline__ void gl_lds16(const void* g, void* l){
  __builtin_amdgcn_global_load_lds(
      (const __attribute__((address_space(1))) unsigned int*)g,
      (__attribute__((address_space(3))) unsigned int*)l, 16, 0, 0);
}

// ---------------- K1: per-head QKV projection + xnorm(v), V transposed ----------------
// blockIdx.y >= H_: weight-conversion slabs (folded former k_cvt).
__device__ __forceinline__ void proj_mfma(const unsigned char* X, const unsigned char* W,
                                          int wid, int l15, int g4, f32x4 acc[4])
{
  f32x4 z = {0.f,0.f,0.f,0.f};
  acc[0]=z; acc[1]=z; acc[2]=z; acc[3]=z;
  #pragma unroll
  for (int kk=0;kk<2;++kk){
    int kbyte = kk*64 + g4*16;
    bf16x8 a = ldfrag(X, wid*16 + l15, kbyte);
    #pragma unroll
    for (int t=0;t<4;++t){
      bf16x8 w = ldfrag(W, t*16 + l15, kbyte);
      acc[t] = __builtin_amdgcn_mfma_f32_16x16x32_bf16(a, w, acc[t], 0, 0, 0);
    }
  }
}

__global__ __launch_bounds__(256) void k_proj(
    const float* __restrict__ qin, const float* __restrict__ kin, const float* __restrict__ vin,
    const float* __restrict__ Wq, const float* __restrict__ Wk, const float* __restrict__ Wv,
    u16* __restrict__ qp, u16* __restrict__ kp, u16* __restrict__ vnT,
    const float* __restrict__ Wo, const float* __restrict__ Wsq,
    u16* __restrict__ wo16, u16* __restrict__ wsq16)
{
  __shared__ alignas(16) unsigned char sm[49152];
  if (blockIdx.y >= H_){
    int cblk = (blockIdx.y - H_)*64 + blockIdx.x;
    int n4 = (E_*E_)/4;
    for (int i = cblk*256 + threadIdx.x; i < 2*n4; i += 128*256){
      const float4* src; ushort4* dst; int j;
      if (i < n4){ src=(const float4*)Wo;  dst=(ushort4*)wo16;  j=i; }
      else       { src=(const float4*)Wsq; dst=(ushort4*)wsq16; j=i-n4; }
      float4 v = src[j];
      ushort4 p; p.x=f2bf(v.x); p.y=f2bf(v.y); p.z=f2bf(v.z); p.w=f2bf(v.w);
      dst[j] = p;
    }
    return;
  }
  const int XQ=0, XK=8192, XV=16384, WQS=24576, WKS=32768, WVS=40960;
  int tid = threadIdx.x, lane = tid&63, wid = tid>>6;
  int l15 = lane&15, g4 = lane>>4;
  int tb = blockIdx.x*64;
  int h  = blockIdx.y;
  int b  = tb >> 11;
  int sbase = tb & 2047;
  int bh = b*H_ + h;

  { // stage X tiles and W tiles, fp32 -> bf16 via cvt_pk
    int rl = tid>>2;
    int d0 = (tid&3)*16;
    const float* xs[3] = { qin, kin, vin };
    const float* wsrc[3] = { Wq, Wk, Wv };
    const int xoff[3] = {XQ,XK,XV}, woff[3] = {WQS,WKS,WVS};
    #pragma unroll
    for (int m3=0;m3<3;++m3){
      const float4* gx = reinterpret_cast<const float4*>(xs[m3] + (size_t)(tb+rl)*E_ + h*HD_ + d0);
      float4 a=gx[0], bb=gx[1], c=gx[2], d=gx[3];
      *(uint4*)(sm + xoff[m3] + rl*128 + SWZ(rl, d0*2))    = pack8(a,bb);
      *(uint4*)(sm + xoff[m3] + rl*128 + SWZ(rl, d0*2+16)) = pack8(c,d);
      const float4* gw = reinterpret_cast<const float4*>(wsrc[m3] + rl*64 + d0);
      float4 e=gw[0], f=gw[1], g2=gw[2], h2=gw[3];
      *(uint4*)(sm + woff[m3] + rl*128 + SWZ(rl, d0*2))    = pack8(e,f);
      *(uint4*)(sm + woff[m3] + rl*128 + SWZ(rl, d0*2+16)) = pack8(g2,h2);
    }
  }
  __syncthreads();

  f32x4 qacc[4], kacc[4], vacc[4];
  proj_mfma(sm+XQ, sm+WQS, wid, l15, g4, qacc);
  proj_mfma(sm+XK, sm+WKS, wid, l15, g4, kacc);
  proj_mfma(sm+XV, sm+WVS, wid, l15, g4, vacc);

  {
    float p4r[4] = {0.f,0.f,0.f,0.f};
    #pragma unroll
    for (int t=0;t<4;++t)
      #pragma unroll
      for (int r=0;r<4;++r){ float e = vacc[t][r]; float e2 = e*e; p4r[r] += e2*e2; }
    #pragma unroll
    for (int r=0;r<4;++r){
      float p = p4r[r];
      p += __shfl_xor(p,1); p += __shfl_xor(p,2); p += __shfl_xor(p,4); p += __shfl_xor(p,8);
      p4r[r] = GAMMA / sqrtf(sqrtf(p));
    }
    #pragma unroll
    for (int t=0;t<4;++t)
      #pragma unroll
      for (int r=0;r<4;++r) vacc[t][r] *= p4r[r];
  }

  __syncthreads();   // X/W no longer needed; reuse XQ/XK/XV as output staging

  #pragma unroll
  for (int t=0;t<4;++t){
    int dd = t*16 + l15;
    #pragma unroll
    for (int r=0;r<4;++r){
      int tokl = wid*16 + g4*4 + r;
      *(u16*)(sm + XQ + tokl*128 + SWZ(tokl, dd*2)) = f2bf(qacc[t][r]);
      *(u16*)(sm + XK + tokl*128 + SWZ(tokl, dd*2)) = f2bf(kacc[t][r]);
    }
    #pragma unroll
    for (int r=0;r<4;r+=2){
      int tokl = wid*16 + g4*4 + r;
      *(u32*)(sm + XV + dd*128 + SWZ(dd, tokl*2)) = cvt_pk_bf16(vacc[t][r], vacc[t][r+1]);
    }
  }
  __syncthreads();

  {
    int rl = tid>>2; int c2 = tid&3;
    uint4 q0 = *(const uint4*)(sm + XQ + rl*128 + SWZ(rl, c2*32));
    uint4 q1 = *(const uint4*)(sm + XQ + rl*128 + SWZ(rl, c2*32+16));
    size_t qg = ((size_t)bh*S_ + sbase + rl)*HD_ + c2*16;
    *(uint4*)(qp + qg)     = q0;
    *(uint4*)(qp + qg + 8) = q1;
    uint4 k0 = *(const uint4*)(sm + XK + rl*128 + SWZ(rl, c2*32));
    uint4 k1 = *(const uint4*)(sm + XK + rl*128 + SWZ(rl, c2*32+16));
    *(uint4*)(kp + qg)     = k0;
    *(uint4*)(kp + qg + 8) = k1;
    uint4 v0 = *(const uint4*)(sm + XV + rl*128 + SWZ(rl, c2*32));
    uint4 v1 = *(const uint4*)(sm + XV + rl*128 + SWZ(rl, c2*32+16));
    size_t vg = ((size_t)bh*HD_ + rl)*S_ + sbase + c2*16;
    *(uint4*)(vnT + vg)     = v0;
    *(uint4*)(vnT + vg + 8) = v1;
  }
}

// ---------------- K2: flash attention, KVBLK=128, Fq=2, ONE barrier/tile ----------------
// K in 3-buffer LDS (3x16KB @0), V in 2-buffer (2x16KB @49152) = 80KB/block,
// 2 blocks/CU. Per tile: [vmcnt(4); barrier] -> STAGE_V(t+1), STAGE_K(t+2) ->
// QK/PACK/PV. FIFO vmcnt: queue at top of t = [K(t),V(t),K(t+1)], vmcnt(4)
// drains exactly K(t)+V(t). Never drains to 0 mid-loop.
__global__ __launch_bounds__(256, 2) void k_attn(
    const u16* __restrict__ qp, const u16* __restrict__ kp,
    const u16* __restrict__ vnT, u16* __restrict__ ao)
{
  __shared__ alignas(128) unsigned char sm[81920];   // K: 3x16KB @0; V: 2x16KB @49152
  char* smc = (char*)sm;
  int tid = threadIdx.x, lane = tid&63, wv = tid>>6;
  int l31 = lane&31, hi = lane>>5;
  int qi = wv>>1, kj = wv&1;
  int L = blockIdx.x;
  int xcd = L&7, iw = L>>3;            // iw 0..63
  int bh = xcd*4 + (iw>>4);            // consecutive iw share bh (L1/L2 reuse)
  int qx = iw&15;
  int qb = qx*128;
  int b = bh>>4, h = bh&15;
  const u16* Kb = kp  + (size_t)bh*S_*HD_;
  const u16* Vb = vnT + (size_t)bh*HD_*S_;
  const u16* Qb = qp  + (size_t)bh*S_*HD_;
  int q0 = qb + qi*64;

  bf16x8 qf[2][4];
  #pragma unroll
  for (int f=0;f<2;++f)
    #pragma unroll
    for (int kk=0;kk<4;++kk)
      qf[f][kk] = *reinterpret_cast<const bf16x8*>(Qb + (size_t)(q0 + f*32 + l31)*HD_ + kk*16 + hi*8);

  f32x16 z16 = {};
  f32x16 o[2][2];
  #pragma unroll
  for (int f=0;f<2;++f){ o[f][0] = z16; o[f][1] = z16; }
  f32x2 p4a[2] = {{0.f,0.f},{0.f,0.f}};
  f32x2 p4b[2] = {{0.f,0.f},{0.f,0.f}};

  const char* kSrcC[4]; const char* vSrcC[4];
  #pragma unroll
  for (int c=0;c<4;++c){
    int rk = wv*32 + c*8 + (lane>>3);
    int ck = ((lane&7)*16) ^ ((rk&7)<<4);
    kSrcC[c] = (const char*)Kb + (size_t)rk*128 + ck;
    int rv = wv*16 + c*4 + (lane>>4);
    int cv = ((lane&15)*16) ^ ((rv&15)<<4);
    vSrcC[c] = (const char*)Vb + (size_t)rv*4096 + cv;
  }

  auto STAGE_K = [&](int bsel, int kt){
    char* db = smc + bsel*16384 + wv*4096;
    #pragma unroll
    for (int c=0;c<4;++c) gl_lds16(kSrcC[c] + (size_t)kt*16384, db + c*1024);
  };
  auto STAGE_V = [&](int bsel, int kt){
    char* db = smc + 49152 + bsel*16384 + wv*4096;
    #pragma unroll
    for (int c=0;c<4;++c) gl_lds16(vSrcC[c] + (size_t)kt*256, db + c*1024);
  };

  auto PACK = [&](const f32x16& e, u32 (&w)[4][2], f32x2& pa){
    #pragma unroll
    for (int j=0;j<8;++j){
      const int g=j>>1, i=j&1;
      float a = e[4*g+2*i], c = e[4*g+2*i+1];
      f32x2 pr = {a, c};
      f32x2 e2;
      asm("v_pk_mul_f32 %0, %1, %1" : "=v"(e2) : "v"(pr));
      asm("v_pk_fma_f32 %0, %1, %1, %0" : "+v"(pa) : "v"(e2));
      w[g][i] = cvt_pk_bf16(a, c);
    }
  };
  auto AFRAG = [&](u32 (&w)[4][2], int s) -> bf16x8 {
    u32 a0 = w[2*s][0], b0 = w[2*s+1][0];
    u32 a1 = w[2*s][1], b1 = w[2*s+1][1];
    asm("v_permlane32_swap_b32 %0, %1" : "+v"(a0), "+v"(b0));
    asm("v_permlane32_swap_b32 %0, %1" : "+v"(a1), "+v"(b1));
    typedef __attribute__((ext_vector_type(4))) unsigned int u32x4t;
    u32x4t fw = {a0, a1, b0, b1};
    return __builtin_bit_cast(bf16x8, fw);
  };

  auto QK = [&](const unsigned char* K_, int s2, f32x16& E0, f32x16& E1){
    bf16x8 ka[4];
    #pragma unroll
    for (int kk=0;kk<4;++kk) ka[kk] = ldfrag(K_, kj*64 + s2*32 + l31, kk*32 + hi*16);
    E0 = z16; E1 = z16;
    __builtin_amdgcn_s_setprio(1);
    #pragma unroll
    for (int kk=0;kk<4;++kk){
      E0 = __builtin_amdgcn_mfma_f32_32x32x16_bf16(ka[kk], qf[0][kk], E0, 0,0,0);
      E1 = __builtin_amdgcn_mfma_f32_32x32x16_bf16(ka[kk], qf[1][kk], E1, 0,0,0);
    }
    __builtin_amdgcn_s_setprio(0);
  };

  auto PVF = [&](const unsigned char* V_, int s2, u32 (&w0)[4][2], u32 (&w1)[4][2]){
    bf16x8 vb[2][2];
    #pragma unroll
    for (int s=0;s<2;++s){
      vb[s][0] = ldfragV(V_, l31,    kj*128 + s2*64 + s*32 + hi*16);
      vb[s][1] = ldfragV(V_, 32+l31, kj*128 + s2*64 + s*32 + hi*16);
    }
    __builtin_amdgcn_s_setprio(1);
    #pragma unroll
    for (int s=0;s<2;++s){
      bf16x8 ef0 = AFRAG(w0, s);
      bf16x8 ef1 = AFRAG(w1, s);
      o[0][0] = __builtin_amdgcn_mfma_f32_32x32x16_bf16(ef0, vb[s][0], o[0][0], 0,0,0);
      o[0][1] = __builtin_amdgcn_mfma_f32_32x32x16_bf16(ef0, vb[s][1], o[0][1], 0,0,0);
      o[1][0] = __builtin_amdgcn_mfma_f32_32x32x16_bf16(ef1, vb[s][0], o[1][0], 0,0,0);
      o[1][1] = __builtin_amdgcn_mfma_f32_32x32x16_bf16(ef1, vb[s][1], o[1][1], 0,0,0);
    }
    __builtin_amdgcn_s_setprio(0);
  };

  const int NT = S_/128;   // 16
  // prologue: issue K(0), V(0), K(1)  (order matters for FIFO vmcnt math)
  STAGE_K(0, 0); STAGE_V(0, 0); STAGE_K(1, 1);

  f32x16 eA0, eA1, eB0, eB1;
  u32 wA0[4][2], wA1[4][2], wB0[4][2], wB1[4][2];

  #pragma unroll 1
  for (int t=0; t<NT; ++t){
    if (t < NT-1) { asm volatile("s_waitcnt vmcnt(4)" ::: "memory"); }
    else          { asm volatile("s_waitcnt vmcnt(0)" ::: "memory"); }
    __builtin_amdgcn_s_barrier();      // the ONLY barrier per tile
    asm volatile("" ::: "memory");
    if (t+1 < NT) STAGE_V((t+1)&1, t+1);   // overwrites buffer last read at PV(t-1)
    if (t+2 < NT) STAGE_K((t+2)%3, t+2);   // 3-buf slot last read at QK(t-1)

    const unsigned char* K_ = sm + (t%3)*16384;
    const unsigned char* V_ = sm + 49152 + (t&1)*16384;

    QK(K_, 0, eA0, eA1);
    QK(K_, 1, eB0, eB1);
    PACK(eA0, wA0, p4a[0]);
    PACK(eA1, wA1, p4a[1]);
    PVF(V_, 0, wA0, wA1);
    PACK(eB0, wB0, p4b[0]);
    PACK(eB1, wB1, p4b[1]);
    PVF(V_, 1, wB0, wB1);
  }

  float p4f[2];
  #pragma unroll
  for (int f=0;f<2;++f) p4f[f] = p4a[f].x + p4a[f].y + p4b[f].x + p4b[f].y;

  __syncthreads();
  float* red  = (float*)smc;
  float* redp = (float*)(smc + 32768);
  if (kj==1){
    #pragma unroll
    for (int f=0;f<2;++f){
      #pragma unroll
      for (int ds=0;ds<2;++ds){
        float* dst = red + ((((qi*2+f)*2+ds)*64 + lane)*16);
        #pragma unroll
        for (int r4=0;r4<4;++r4)
          *(float4*)(dst + r4*4) = make_float4(o[f][ds][r4*4],o[f][ds][r4*4+1],o[f][ds][r4*4+2],o[f][ds][r4*4+3]);
      }
      redp[(qi*2+f)*64 + lane] = p4f[f];
    }
  }
  __syncthreads();
  if (kj==0){
    #pragma unroll
    for (int f=0;f<2;++f){
      #pragma unroll
      for (int ds=0;ds<2;++ds){
        const float* srcp = red + ((((qi*2+f)*2+ds)*64 + lane)*16);
        #pragma unroll
        for (int r4=0;r4<4;++r4){
          float4 t = *(const float4*)(srcp + r4*4);
          o[f][ds][r4*4]+=t.x; o[f][ds][r4*4+1]+=t.y; o[f][ds][r4*4+2]+=t.z; o[f][ds][r4*4+3]+=t.w;
        }
      }
      p4f[f] += redp[(qi*2+f)*64 + lane];
      p4f[f] += __shfl_xor(p4f[f], 32);
    }
    float sc0 = GAMMA * rsqrtf(sqrtf(p4f[0]));
    float sc1 = GAMMA * rsqrtf(sqrtf(p4f[1]));
    #pragma unroll
    for (int f=0;f<2;++f){
      #pragma unroll
      for (int r=0;r<16;++r){
        int qrow = (r&3) + 8*(r>>2) + 4*hi;
        float scr = __shfl(f==0 ? sc0 : sc1, qrow);
        size_t n = (size_t)b*S_ + q0 + f*32 + qrow;
        u16* dst = ao + n*E_ + h*HD_;
        dst[l31]    = f2bf(o[f][0][r] * scr);
        dst[32+l31] = f2bf(o[f][1][r] * scr);
      }
    }
  }
}

// ---------------- K3/K5: 128x128-tile bf16 GEMM, 64x64 per wave (1:1 MFMA:ds_read) ----------------
template<int MODE>
__global__ __launch_bounds__(256, 2) void k_gemm(
    const u16* __restrict__ A, const u16* __restrict__ Bw,
    const float* __restrict__ bias, const float* __restrict__ auxf,
    const u16* __restrict__ aux16, float* __restrict__ out32, u16* __restrict__ out16)
{
  __shared__ alignas(128) unsigned char sm[65536];   // 2 x (A 16KB + B 16KB)
  char* smc = (char*)sm;
  int tid = threadIdx.x, lane = tid&63, wv = tid>>6;
  int l31 = lane&31, hi = lane>>5;
  int wr = wv>>1, wc = wv&1;
  int LL = (blockIdx.x & 7)*32 + (blockIdx.x >> 3);
  int mt = LL >> 3, nt = LL & 7;                      // 32 m-tiles x 8 n-tiles
  int m0 = mt*128, n0 = nt*128;

  const char* aS[4]; const char* bS[4];
  #pragma unroll
  for (int c=0;c<4;++c){
    int off = wv*4096 + c*1024 + lane*16;
    int r = off>>7, cl = off&127;
    int cs = cl ^ ((r&7)<<4);
    aS[c] = (const char*)A  + ((size_t)(m0+r)*E_)*2 + cs;
    bS[c] = (const char*)Bw + ((size_t)(n0+r)*E_)*2 + cs;
  }

  auto STAGE = [&](int bsel, int t){
    char* db = smc + bsel*32768 + wv*4096;
    size_t kb2 = (size_t)t*128;
    #pragma unroll
    for (int c=0;c<4;++c) gl_lds16(aS[c] + kb2, db + c*1024);
    #pragma unroll
    for (int c=0;c<4;++c) gl_lds16(bS[c] + kb2, db + 16384 + c*1024);
  };

  f32x16 acc[2][2] = {{{}, {}}, {{}, {}}};

  const int NK = E_/64;   // 16
  STAGE(0, 0); STAGE(1, 1);

  #pragma unroll 1
  for (int t=0; t<NK; ++t){
    if (t < NK-1) { asm volatile("s_waitcnt vmcnt(8)" ::: "memory"); }
    else          { asm volatile("s_waitcnt vmcnt(0)" ::: "memory"); }
    __builtin_amdgcn_s_barrier();
    asm volatile("" ::: "memory");

    const unsigned char* Ap_ = sm + (t&1)*32768;
    const unsigned char* Bp_ = Ap_ + 16384;
    #pragma unroll
    for (int kk=0;kk<4;++kk){
      int kbyte = kk*32 + hi*16;
      bf16x8 a0 = ldfrag(Ap_, wr*64 + l31,      kbyte);
      bf16x8 a1 = ldfrag(Ap_, wr*64 + 32 + l31, kbyte);
      bf16x8 b0 = ldfrag(Bp_, wc*64 + l31,      kbyte);
      bf16x8 b1 = ldfrag(Bp_, wc*64 + 32 + l31, kbyte);
      __builtin_amdgcn_s_setprio(1);
      acc[0][0] = __builtin_amdgcn_mfma_f32_32x32x16_bf16(a0, b0, acc[0][0], 0,0,0);
      acc[0][1] = __builtin_amdgcn_mfma_f32_32x32x16_bf16(a0, b1, acc[0][1], 0,0,0);
      acc[1][0] = __builtin_amdgcn_mfma_f32_32x32x16_bf16(a1, b0, acc[1][0], 0,0,0);
      acc[1][1] = __builtin_amdgcn_mfma_f32_32x32x16_bf16(a1, b1, acc[1][1], 0,0,0);
      __builtin_amdgcn_s_setprio(0);
    }

    asm volatile("" ::: "memory");
    __builtin_amdgcn_s_barrier();
    asm volatile("" ::: "memory");
    if (t+2 < NK) STAGE(t&1, t+2);
  }

  #pragma unroll
  for (int cg=0;cg<2;++cg){
    int col = n0 + wc*64 + cg*32 + l31;
    float bi = bias[col];
    #pragma unroll
    for (int rg=0;rg<2;++rg)
      #pragma unroll
      for (int r=0;r<16;++r){
        int mrow = m0 + wr*64 + rg*32 + (r&3) + 8*(r>>2) + 4*hi;
        size_t idx = (size_t)mrow*E_ + col;
        float v = acc[rg][cg][r] + bi;
        if (MODE == 0){
          out16[idx] = f2bf(v + auxf[idx]);
        } else {
          float gg = 1.f/(1.f + __expf(-v));
          out32[idx] = bf2f(aux16[idx]) * gg;
        }
      }
  }
}

// ---------------- K4: LayerNorm over embed dim; bf16 in -> bf16 out ----------------
__global__ __launch_bounds__(256) void k_ln(
    const u16* __restrict__ xin, const float* __restrict__ lnw, const float* __restrict__ lnb,
    u16* __restrict__ xout)
{
  __shared__ float red[8];
  __shared__ float stats[2];
  int row = blockIdx.x, tid = threadIdx.x;
  ushort4 xr = reinterpret_cast<const ushort4*>(xin + (size_t)row*E_)[tid];
  float x0 = bf2f(xr.x), x1 = bf2f(xr.y), x2 = bf2f(xr.z), x3 = bf2f(xr.w);
  float s  = x0 + x1 + x2 + x3;
  float s2 = x0*x0 + x1*x1 + x2*x2 + x3*x3;
  #pragma unroll
  for (int m=1;m<64;m<<=1){ s += __shfl_xor(s,m); s2 += __shfl_xor(s2,m); }
  if ((tid&63)==0){ red[tid>>6] = s; red[4+(tid>>6)] = s2; }
  __syncthreads();
  if (tid==0){
    float ts  = red[0]+red[1]+red[2]+red[3];
    float ts2 = red[4]+red[5]+red[6]+red[7];
    float mu  = ts * (1.f/E_);
    float var = ts2 * (1.f/E_) - mu*mu;
    stats[0] = mu; stats[1] = rsqrtf(var + 1e-5f);
  }
  __syncthreads();
  float mu = stats[0], rstd = stats[1];
  float4 w  = reinterpret_cast<const float4*>(lnw)[tid];
  float4 bb = reinterpret_cast<const float4*>(lnb)[tid];
  ushort4 p;
  p.x = f2bf((x0-mu)*rstd*w.x + bb.x);
  p.y = f2bf((x1-mu)*rstd*w.y + bb.y);
  p.z = f2bf((x2-mu)*rstd*w.z + bb.z);
  p.w = f2bf((x3-mu)*rstd*w.w + bb.w);
  reinterpret_cast<ushort4*>(xout + (size_t)row*E_)[tid] = p;
}

// ---------------- host launch ----------------
extern "C" void kernel_launch(void* const* d_in, const int* in_sizes, int n_in,
                              void* d_out, int out_size, void* d_ws, size_t ws_size,
                              hipStream_t stream)
{
  const float* value = (const float*)d_in[0];
  const float* key   = (const float*)d_in[1];
  const float* query = (const float*)d_in[2];
  const float* Wq    = (const float*)d_in[3];
  const float* Wk    = (const float*)d_in[4];
  const float* Wv    = (const float*)d_in[5];
  const float* Wo    = (const float*)d_in[6];
  const float* bo    = (const float*)d_in[7];
  const float* lnw   = (const float*)d_in[8];
  const float* lnb   = (const float*)d_in[9];
  const float* Wsq   = (const float*)d_in[10];
  const float* bsq   = (const float*)d_in[11];
  float* out = (float*)d_out;

  char* ws = (char*)d_ws;
  const size_t MB = 1ull<<20;
  u16*   qp     = (u16*)(ws + 0*MB);    // K1->K2
  u16*   kp     = (u16*)(ws + 8*MB);    // K1->K2
  u16*   vnT    = (u16*)(ws + 16*MB);   // K1->K2
  u16*   ao     = (u16*)(ws + 24*MB);   // K2->K3 (8MB)
  u16*   xres16 = (u16*)(ws + 8*MB);    // K3->K4 (8MB, over kp)
  u16*   x16    = (u16*)(ws + 16*MB);   // K4->K5 (8MB, over vnT)
  u16*   wo16   = (u16*)(ws + 48*MB);
  u16*   wsq16  = (u16*)(ws + 50*MB);

  k_proj<<<dim3(N_/64, H_+2), 256, 0, stream>>>(query, key, value, Wq, Wk, Wv,
                                                qp, kp, vnT, Wo, Wsq, wo16, wsq16);
  k_attn<<<512, 256, 0, stream>>>(qp, kp, vnT, ao);
  k_gemm<0><<<256, 256, 0, stream>>>(ao, wo16, bo, query, (const u16*)nullptr, (float*)nullptr, xres16);
  k_ln  <<<N_, 256, 0, stream>>>(xres16, lnw, lnb, x16);
  k_gemm<1><<<256, 256, 0, stream>>>(x16, wsq16, bsq, (const float*)nullptr, x16, out, (u16*)nullptr);
}